// Round 15
// baseline (185.231 us; speedup 1.0000x reference)
//
#include <hip/hip_runtime.h>
#include <hip/hip_bf16.h>
#include <stdint.h>
#include <math.h>

using bf16x8 = __attribute__((ext_vector_type(8))) short;
using bf16x4 = __attribute__((ext_vector_type(4))) short;
using f32x4  = __attribute__((ext_vector_type(4))) float;

#define DEV static __device__ __forceinline__

// SESSION LEDGER:
//  - r6/7: v_cvt_pk_bf16_f32 INLINE ASM => NaN. BANNED. packbf (compiler) green.
//  - r4/r12: exp2-domain q-prescale => absmax 5.86e-3 (deterministic). BANNED.
//    q prescale stays EXACT POW2 (0.125) + __expf.
//  - r8/r11: attn partition-invariant (serial-chain-bound). Chain levers only.
//  - r10: BK=64 swizzled-glds GEMM green. If unexplained NaN: revert to BK=32.
//  - r14: RoPE+V-transpose fused into GEMM1 epilogue (green, bit-stable).
//  - r15 (this): attn KVBLK 64->128 (2 KV tiles/iter): barriers 32->16,
//    shfl/skip chains halved per key. All fragment maps preserved (K row
//    relation unchanged; V rows 128 shorts w/ p^(d&15) involution; PV slot
//    map unchanged with kf 0..3). If red: revert attn to r14 form.

DEV float bf2f(short s) {
  union { unsigned u; float f; } v; v.u = ((unsigned)(unsigned short)s) << 16; return v.f;
}
DEV short f2bf(float f) {
  union { float ff; unsigned u; } v; v.ff = f;
  unsigned r = v.u + 0x7fffu + ((v.u >> 16) & 1u);
  return (short)(r >> 16);
}
DEV unsigned packbf(float a, float b) {  // lo16 = RNE(a), hi16 = RNE(b)
  __hip_bfloat162 h = __float22bfloat162_rn(make_float2(a, b));
  union { __hip_bfloat162 h2; unsigned u; } v; v.h2 = h; return v.u;
}

DEV f32x4 mfma16x16x32(bf16x8 a, bf16x8 b, f32x4 c) {
  return __builtin_amdgcn_mfma_f32_16x16x32_bf16(a, b, c, 0, 0, 0);
}

DEV void glds16(const void* g, void* l) {
  __builtin_amdgcn_global_load_lds(
      (__attribute__((address_space(1))) void*)(uintptr_t)(g),
      (__attribute__((address_space(3))) void*)(l), 16, 0, 0);
}

#define B_   2
#define N_   2048
#define DIM_ 1024
#define H_   16
#define DH_  64
#define BH_  (B_ * H_)
#define BN_  (B_ * N_)

// ---------------------------------------------------------------------------
// 1) cos/sin table: cs[(n*32+j)*2] = cos(n * 10000^(-2j/64)), +1 = sin
// ---------------------------------------------------------------------------
__global__ void cs_kernel(float* __restrict__ cs) {
  int tid = blockIdx.x * blockDim.x + threadIdx.x;   // 65536 = 2048 * 32
  int n = tid >> 5, j = tid & 31;
  float inv = powf(10000.0f, -(float)(2 * j) / 64.0f);
  float ang = (float)n * inv;
  cs[2 * tid]     = cosf(ang);
  cs[2 * tid + 1] = sinf(ang);
}

// ---------------------------------------------------------------------------
// 2) fp32 -> bf16 elementwise (for x)
// ---------------------------------------------------------------------------
__global__ __launch_bounds__(256) void conv_kernel(const float* __restrict__ src,
                                                   short* __restrict__ dst) {
  int i = (blockIdx.x * 256 + threadIdx.x) * 8;
  float4 a = *(const float4*)(src + i);
  float4 b = *(const float4*)(src + i + 4);
  bf16x8 o;
  o[0] = f2bf(a.x); o[1] = f2bf(a.y); o[2] = f2bf(a.z); o[3] = f2bf(a.w);
  o[4] = f2bf(b.x); o[5] = f2bf(b.y); o[6] = f2bf(b.z); o[7] = f2bf(b.w);
  *(bf16x8*)(dst + i) = o;
}

// ---------------------------------------------------------------------------
// 3) transpose fp32 [R][C] -> bf16 [C][R]  (64x64 LDS tiles)
//    PERM: for q/k thirds (cb < 2048) write row cb + pi(cl):
//    pi(d): j=d>>1, s=d&1 -> 32*(j>>4) + 16*s + (j&15). RoPE pairs land in
//    the SAME lane of the GEMM C-fragment (ni pairs).
// ---------------------------------------------------------------------------
template <bool PERM>
__global__ __launch_bounds__(256) void transw_kernel(const float* __restrict__ src,
                                                     short* __restrict__ dst,
                                                     int R, int C) {
  __shared__ unsigned short lds[64 * 65];
  const int t = threadIdx.x;
  const int cb = blockIdx.x * 64, rb = blockIdx.y * 64;
  #pragma unroll
  for (int pass = 0; pass < 4; ++pass) {
    int r  = pass * 16 + (t >> 4);
    int cc = (t & 15) * 4;
    float4 v = *(const float4*)(src + (size_t)(rb + r) * C + cb + cc);
    lds[(cc + 0) * 65 + r] = (unsigned short)f2bf(v.x);
    lds[(cc + 1) * 65 + r] = (unsigned short)f2bf(v.y);
    lds[(cc + 2) * 65 + r] = (unsigned short)f2bf(v.z);
    lds[(cc + 3) * 65 + r] = (unsigned short)f2bf(v.w);
  }
  __syncthreads();
  const int cl = t >> 2, chunk = t & 3;
  bf16x8 o0, o1;
  #pragma unroll
  for (int j = 0; j < 8; ++j) {
    o0[j] = (short)lds[cl * 65 + chunk * 16 + j];
    o1[j] = (short)lds[cl * 65 + chunk * 16 + 8 + j];
  }
  int ocl = cl;
  if (PERM && cb < 2048) {
    int j = cl >> 1, s2 = cl & 1;
    ocl = ((j >> 4) << 5) + (s2 << 4) + (j & 15);
  }
  size_t off = (size_t)(cb + ocl) * R + rb + chunk * 16;
  *(bf16x8*)(dst + off)     = o0;
  *(bf16x8*)(dst + off + 8) = o1;
}

// ---------------------------------------------------------------------------
// 4) GEMM: C = A @ BT^T. 128x128 tile, BK=64, chunk-XOR swizzled glds source
//    (r10-proven). MODE 0: f32 output. MODE 2: fused QKV epilogue.
// ---------------------------------------------------------------------------
template <int MODE>
__global__ __launch_bounds__(256) void gemm_bt_kernel(const short* __restrict__ A,
                                                      const short* __restrict__ BT,
                                                      float* __restrict__ Cout,
                                                      short* __restrict__ qb,
                                                      short* __restrict__ kb,
                                                      short* __restrict__ vT,
                                                      const float* __restrict__ cs,
                                                      int M, int N, int K, int gx) {
  __shared__ short As[128 * 64];
  __shared__ short Bs[128 * 64];
  const int nwg = gridDim.x;
  const int bid = blockIdx.x;
  const int swz = (bid & 7) * (nwg >> 3) + (bid >> 3);  // bijective: nwg%8==0
  const int bx = swz % gx, by = swz / gx;
  const int t = threadIdx.x;
  const int lane = t & 63, w = t >> 6;
  const int c = lane & 15, g = lane >> 4;
  const int wm = w >> 1, wn = w & 1;
  const int mbase = by * 128, nbase = bx * 128;
  const short* Ab = A + (size_t)mbase * K;
  const short* Bb = BT + (size_t)nbase * K;
  f32x4 acc[4][4] = {};
  for (int kb2 = 0; kb2 < K; kb2 += 64) {
    #pragma unroll
    for (int i = 0; i < 4; ++i) {
      const int idx = i * 256 + t;             // 0..1023 chunk id
      const int row = idx >> 3, p = idx & 7;
      const int gc = ((p ^ (row & 7)) << 3);   // source chunk pre-swizzle
      glds16(Ab + (size_t)row * K + kb2 + gc, As + idx * 8);
      glds16(Bb + (size_t)row * K + kb2 + gc, Bs + idx * 8);
    }
    __syncthreads();
    bf16x8 af[4][2], bfr[4][2];
    #pragma unroll
    for (int mi = 0; mi < 4; ++mi) {
      const int r = wm * 64 + mi * 16 + c;
      #pragma unroll
      for (int kk = 0; kk < 2; ++kk)
        af[mi][kk] = *(const bf16x8*)&As[r * 64 + (((kk * 4 + g) ^ (r & 7)) << 3)];
    }
    #pragma unroll
    for (int ni = 0; ni < 4; ++ni) {
      const int r = wn * 64 + ni * 16 + c;
      #pragma unroll
      for (int kk = 0; kk < 2; ++kk)
        bfr[ni][kk] = *(const bf16x8*)&Bs[r * 64 + (((kk * 4 + g) ^ (r & 7)) << 3)];
    }
    #pragma unroll
    for (int kk = 0; kk < 2; ++kk)
      #pragma unroll
      for (int mi = 0; mi < 4; ++mi)
        #pragma unroll
        for (int ni = 0; ni < 4; ++ni)
          acc[mi][ni] = mfma16x16x32(af[mi][kk], bfr[ni][kk], acc[mi][ni]);
    __syncthreads();
  }
  if constexpr (MODE == 0) {
    #pragma unroll
    for (int mi = 0; mi < 4; ++mi) {
      const int row = mbase + wm * 64 + mi * 16 + g * 4;
      #pragma unroll
      for (int ni = 0; ni < 4; ++ni) {
        const int col = nbase + wn * 64 + ni * 16 + c;
        #pragma unroll
        for (int r = 0; r < 4; ++r)
          Cout[(size_t)(row + r) * N + col] = acc[mi][ni][r];
      }
    }
  } else {
    const int col0 = nbase + wn * 64;     // head base; one head per warp
    const int i3 = col0 >> 10;            // 0=q, 1=k, 2=v
    const int h  = (col0 >> 6) & 15;
    if (i3 < 2) {
      short* dst0 = (i3 == 0) ? qb : kb;
      const float sc = (i3 == 0) ? 0.125f : 1.0f;
      #pragma unroll
      for (int mi = 0; mi < 4; ++mi) {
        const int row0 = mbase + wm * 64 + mi * 16 + g * 4;
        #pragma unroll
        for (int r = 0; r < 4; ++r) {
          const int row = row0 + r;
          const int n = row & 2047, b = row >> 11;
          short* dp = dst0 + ((size_t)(b * H_ + h) * N_ + n) * DH_;
          float2 cs0 = ((const float2*)cs)[n * 32 + c];
          float2 cs1 = ((const float2*)cs)[n * 32 + c + 16];
          float t1 = acc[mi][0][r], t2 = acc[mi][1][r];
          float t3 = acc[mi][2][r], t4 = acc[mi][3][r];
          unsigned u0 = packbf((t1 * cs0.x - t2 * cs0.y) * sc,
                               (t1 * cs0.y + t2 * cs0.x) * sc);
          unsigned u1 = packbf((t3 * cs1.x - t4 * cs1.y) * sc,
                               (t3 * cs1.y + t4 * cs1.x) * sc);
          *(unsigned*)(dp + 2 * c)      = u0;   // d = 2c, 2c+1
          *(unsigned*)(dp + 32 + 2 * c) = u1;   // d = 2c+32, 2c+33
        }
      }
    } else {
      #pragma unroll
      for (int mi = 0; mi < 4; ++mi) {
        const int row0 = mbase + wm * 64 + mi * 16 + g * 4;
        const int n0 = row0 & 2047, b = row0 >> 11;
        const int bh = b * H_ + h;
        #pragma unroll
        for (int ni = 0; ni < 4; ++ni) {
          const int dd = ni * 16 + c;
          bf16x4 ov;
          #pragma unroll
          for (int r = 0; r < 4; ++r) ov[r] = f2bf(acc[mi][ni][r]);
          *(bf16x4*)(vT + ((size_t)bh * DH_ + dd) * N_ + n0) = ov;
        }
      }
    }
  }
}

// ---------------------------------------------------------------------------
// 7) Flash attention — KVBLK=128 (2 KV tiles per iteration, 16 iterations).
//    K tile [128 rows][64] with chunk relation p^(row&7) (unchanged);
//    V tile [64 d][128] with 16-chunk involution p^(d&15).
//    PV slot map unchanged: j = kf*32 + (ii<4 ? g*4+ii : 16+g*4+ii-4),
//    kf 0..3, pf[qf][kf] = {s[2kf][0..3], s[2kf+1][0..3]}.
// ---------------------------------------------------------------------------
__global__ __launch_bounds__(256) void attn_kernel(const short* __restrict__ qb,
                                                   const short* __restrict__ kb,
                                                   const short* __restrict__ vT,
                                                   short* __restrict__ attn_out) {
  __shared__ short Kt[2][8192];   // 16 KB per buf: [row 0..127][chunk 0..7][8]
  __shared__ short Vt[2][8192];   // 16 KB per buf: [d 0..63][chunk 0..15][8]
  const int t = threadIdx.x;
  const int lane = t & 63, w = t >> 6;
  const int c = lane & 15, g = lane >> 4;
  const int bid = blockIdx.x;               // 512 blocks, 1D
  const int xcd = bid & 7, slot = bid >> 3; // slot 0..63
  const int bh = xcd + ((slot >> 4) << 3);  // 16 x-blocks of bh share an XCD
  const int xb = slot & 15;
  const int qbase = xb * 128 + w * 32;
  const short* kbase = kb + (size_t)bh * N_ * DH_;
  const short* vbase = vT + (size_t)bh * DH_ * N_;

  // staging maps: 4 chunks per thread per array
  int k_row[4], k_p[4], k_dst[4], v_d[4], v_p[4], v_dst[4];
  #pragma unroll
  for (int i = 0; i < 4; ++i) {
    const int idx = i * 256 + t;
    k_row[i] = idx >> 3;  k_p[i] = idx & 7;
    k_dst[i] = k_row[i] * 64 + ((k_p[i] ^ (k_row[i] & 7)) << 3);
    v_d[i]   = idx >> 4;  v_p[i] = idx & 15;
    v_dst[i] = v_d[i] * 128 + ((v_p[i] ^ (v_d[i] & 15)) << 3);
  }

  // Q fragments held in registers for the whole kv loop; q pre-scaled 1/8
  bf16x8 qlo[2], qhi[2];
  #pragma unroll
  for (int qf = 0; qf < 2; ++qf) {
    const short* qp = qb + ((size_t)bh * N_ + qbase + qf * 16 + c) * DH_;
    qlo[qf] = *(const bf16x8*)(qp + g * 8);
    qhi[qf] = *(const bf16x8*)(qp + 32 + g * 8);
  }

  float M[2] = {-INFINITY, -INFINITY};
  float L[2] = {0.f, 0.f};
  f32x4 o[4][2] = {};
  bf16x8 kr[4], vr[4];

  // prologue: load tile 0 -> regs, write buf 0, barrier
  #pragma unroll
  for (int i = 0; i < 4; ++i) {
    kr[i] = *(const bf16x8*)(kbase + (size_t)k_row[i] * DH_ + k_p[i] * 8);
    vr[i] = *(const bf16x8*)(vbase + (size_t)v_d[i] * N_ + v_p[i] * 8);
  }
  #pragma unroll
  for (int i = 0; i < 4; ++i) {
    *(bf16x8*)(&Kt[0][k_dst[i]]) = kr[i];
    *(bf16x8*)(&Vt[0][v_dst[i]]) = vr[i];
  }
  __syncthreads();

  for (int it = 0; it < 16; ++it) {
    const int cur = it & 1;
    const int pf_valid = (it + 1 < 16);
    if (pf_valid) {  // issue next-tile loads BEFORE compute (overlap)
      const int kv = (it + 1) * 128;
      #pragma unroll
      for (int i = 0; i < 4; ++i) {
        kr[i] = *(const bf16x8*)(kbase + (size_t)(kv + k_row[i]) * DH_ + k_p[i] * 8);
        vr[i] = *(const bf16x8*)(vbase + (size_t)v_d[i] * N_ + kv + v_p[i] * 8);
      }
    }
    // --- QK^T over 128 keys: s[jt][qf], j = it*128 + jt*16 + g*4 + r ---
    f32x4 s[8][2] = {};
    __builtin_amdgcn_s_setprio(1);
    #pragma unroll
    for (int jt = 0; jt < 8; ++jt) {
      const int r_ = jt * 16 + c;
      const short* kt = &Kt[cur][r_ * 64];
      bf16x8 k0 = *(const bf16x8*)(kt + ((g ^ (r_ & 7)) << 3));
      bf16x8 k1 = *(const bf16x8*)(kt + (((g + 4) ^ (r_ & 7)) << 3));
      #pragma unroll
      for (int qf = 0; qf < 2; ++qf) {
        s[jt][qf] = mfma16x16x32(k0, qlo[qf], s[jt][qf]);
        s[jt][qf] = mfma16x16x32(k1, qhi[qf], s[jt][qf]);
      }
    }
    __builtin_amdgcn_s_setprio(0);
    // --- online softmax over 128 keys: exact-skip rescale + tree sum ---
    bf16x8 pf[2][4];
    #pragma unroll
    for (int qf = 0; qf < 2; ++qf) {
      float mj[8];
      #pragma unroll
      for (int jt = 0; jt < 8; ++jt)
        mj[jt] = fmaxf(fmaxf(s[jt][qf][0], s[jt][qf][1]),
                       fmaxf(s[jt][qf][2], s[jt][qf][3]));
      float mx = fmaxf(fmaxf(fmaxf(mj[0], mj[1]), fmaxf(mj[2], mj[3])),
                       fmaxf(fmaxf(mj[4], mj[5]), fmaxf(mj[6], mj[7])));
      mx = fmaxf(mx, __shfl_xor(mx, 16));
      mx = fmaxf(mx, __shfl_xor(mx, 32));
      if (__any(mx > M[qf])) {   // else corr==expf(0)==1 for all lanes: EXACT skip
        const float mnew = fmaxf(M[qf], mx);
        const float corr = __expf(M[qf] - mnew);  // exp(-inf)=0 first tile
        L[qf] *= corr;
        #pragma unroll
        for (int dt = 0; dt < 4; ++dt) o[dt][qf] *= corr;
        M[qf] = mnew;
      }
      #pragma unroll
      for (int jt = 0; jt < 8; ++jt)
        #pragma unroll
        for (int r = 0; r < 4; ++r)
          s[jt][qf][r] = __expf(s[jt][qf][r] - M[qf]);
      float tj[8];
      #pragma unroll
      for (int jt = 0; jt < 8; ++jt)
        tj[jt] = (s[jt][qf][0] + s[jt][qf][1]) + (s[jt][qf][2] + s[jt][qf][3]);
      float rs = ((tj[0] + tj[1]) + (tj[2] + tj[3])) +
                 ((tj[4] + tj[5]) + (tj[6] + tj[7]));
      rs += __shfl_xor(rs, 16);
      rs += __shfl_xor(rs, 32);
      L[qf] += rs;
      #pragma unroll
      for (int kf = 0; kf < 4; ++kf) {
        union { unsigned u[4]; bf16x8 v; } P;
        P.u[0] = packbf(s[2 * kf][qf][0], s[2 * kf][qf][1]);
        P.u[1] = packbf(s[2 * kf][qf][2], s[2 * kf][qf][3]);
        P.u[2] = packbf(s[2 * kf + 1][qf][0], s[2 * kf + 1][qf][1]);
        P.u[3] = packbf(s[2 * kf + 1][qf][2], s[2 * kf + 1][qf][3]);
        pf[qf][kf] = P.v;
      }
    }
    // --- PV: A = V^T row d (128 wide), slot map j = kf*32 + (ii<4 ? g*4+ii
    //     : 16+g*4+ii-4); LDS chunk of element e is (e>>3)^(d&15) ---
    __builtin_amdgcn_s_setprio(1);
    #pragma unroll
    for (int dt = 0; dt < 4; ++dt) {
      const int d = dt * 16 + c;
      const short* vt = &Vt[cur][d * 128];
      const int dx = d & 15;
      #pragma unroll
      for (int kf = 0; kf < 4; ++kf) {
        const int e0 = kf * 32 + g * 4;
        const int e1 = e0 + 16;
        bf16x4 a0 = *(const bf16x4*)(vt + ((((e0 >> 3) ^ dx) << 3) | (e0 & 7)));
        bf16x4 a1 = *(const bf16x4*)(vt + ((((e1 >> 3) ^ dx) << 3) | (e1 & 7)));
        bf16x8 vf = __builtin_shufflevector(a0, a1, 0, 1, 2, 3, 4, 5, 6, 7);
        o[dt][0] = mfma16x16x32(vf, pf[0][kf], o[dt][0]);
        o[dt][1] = mfma16x16x32(vf, pf[1][kf], o[dt][1]);
      }
    }
    __builtin_amdgcn_s_setprio(0);
    // --- write-late: store prefetched regs into the idle buffer ---
    if (pf_valid) {
      #pragma unroll
      for (int i = 0; i < 4; ++i) {
        *(bf16x8*)(&Kt[cur ^ 1][k_dst[i]]) = kr[i];
        *(bf16x8*)(&Vt[cur ^ 1][v_dst[i]]) = vr[i];
      }
    }
    __syncthreads();
  }

  const int b = bh >> 4, h = bh & 15;
  #pragma unroll
  for (int qf = 0; qf < 2; ++qf) {
    const float inv = 1.0f / L[qf];
    short* op = attn_out + ((size_t)b * N_ + qbase + qf * 16 + c) * (H_ * DH_) + h * DH_;
    #pragma unroll
    for (int dt = 0; dt < 4; ++dt) {
      bf16x4 ov;
      #pragma unroll
      for (int r = 0; r < 4; ++r) ov[r] = f2bf(o[dt][qf][r] * inv);
      *(bf16x4*)(op + dt * 16 + g * 4) = ov;
    }
  }
}

// ---------------------------------------------------------------------------
extern "C" void kernel_launch(void* const* d_in, const int* in_sizes, int n_in,
                              void* d_out, int out_size, void* d_ws, size_t ws_size,
                              hipStream_t stream) {
  const float* x    = (const float*)d_in[0];
  const float* Wqkv = (const float*)d_in[1];
  const float* Wout = (const float*)d_in[2];
  char* ws = (char*)d_ws;
  // workspace layout (MiB offsets)
  short* xb    = (short*)(ws);                        // 8 MiB  [4096][1024]
  short* WqkvT = (short*)(ws + ((size_t)8 << 20));    // 6 MiB  [3072][1024] (perm'd q/k cols)
  short* WoutT = (short*)(ws + ((size_t)14 << 20));   // 2 MiB  [1024][1024]
  short* qb    = (short*)(ws + ((size_t)40 << 20));   // 8 MiB  [32][2048][64]
  short* kb    = (short*)(ws + ((size_t)48 << 20));   // 8 MiB
  short* vT    = (short*)(ws + ((size_t)56 << 20));   // 8 MiB  [32][64][2048]
  short* attn  = (short*)(ws + ((size_t)64 << 20));   // 8 MiB  [4096][1024]
  float* cs    = (float*)(ws + ((size_t)72 << 20));   // 0.5 MiB [2048][32][2]

  cs_kernel<<<dim3(256), 256, 0, stream>>>(cs);
  conv_kernel<<<dim3(2048), 256, 0, stream>>>(x, xb);                              // x -> bf16
  transw_kernel<true><<<dim3(48, 16), 256, 0, stream>>>(Wqkv, WqkvT, 1024, 3072);  // Wqkv^T (perm)
  transw_kernel<false><<<dim3(16, 16), 256, 0, stream>>>(Wout, WoutT, 1024, 1024); // Wout^T
  gemm_bt_kernel<2><<<dim3(768), 256, 0, stream>>>(xb, WqkvT, nullptr, qb, kb, vT, cs,
                                                   4096, 3072, 1024, 24);
  attn_kernel<<<dim3(512), 256, 0, stream>>>(qb, kb, vT, attn);
  gemm_bt_kernel<0><<<dim3(256), 256, 0, stream>>>(attn, WoutT, (float*)d_out,
                                                   nullptr, nullptr, nullptr, nullptr,
                                                   4096, 1024, 1024, 8);
}

// Round 16
// 160.299 us; speedup vs baseline: 1.1555x; 1.1555x over previous
//
#include <hip/hip_runtime.h>
#include <hip/hip_bf16.h>
#include <stdint.h>
#include <math.h>

using bf16x8 = __attribute__((ext_vector_type(8))) short;
using bf16x4 = __attribute__((ext_vector_type(4))) short;
using f32x4  = __attribute__((ext_vector_type(4))) float;

#define DEV static __device__ __forceinline__

// SESSION LEDGER:
//  - r6/7: v_cvt_pk_bf16_f32 INLINE ASM => NaN. BANNED. packbf (compiler) green.
//  - r4/r12: exp2-domain q-prescale => absmax 5.86e-3 (deterministic). BANNED.
//    q prescale stays EXACT POW2 (0.125) + __expf.
//  - attn design-space mapped: r8 Q-split REGRESS (2x staging), r11 KV-split
//    NULL (+combine), r13 chain-cuts NULL, r15 KVBLK=128 REGRESS (LDS/VGPR ->
//    occupancy 17.6->11%). r14 form (KVBLK=64, 128 q-rows, 2 blk/CU) is the
//    measured local optimum — PARKED.
//  - r10: BK=64 swizzled-glds GEMM green. If unexplained NaN: revert to BK=32.
//  - r14: RoPE+V-transpose fused into GEMM1 epilogue (green, bit-stable).
//  - r16 (this): exact r14 source — return-to-green anchor after r15 regress.

DEV float bf2f(short s) {
  union { unsigned u; float f; } v; v.u = ((unsigned)(unsigned short)s) << 16; return v.f;
}
DEV short f2bf(float f) {
  union { float ff; unsigned u; } v; v.ff = f;
  unsigned r = v.u + 0x7fffu + ((v.u >> 16) & 1u);
  return (short)(r >> 16);
}
DEV unsigned packbf(float a, float b) {  // lo16 = RNE(a), hi16 = RNE(b)
  __hip_bfloat162 h = __float22bfloat162_rn(make_float2(a, b));
  union { __hip_bfloat162 h2; unsigned u; } v; v.h2 = h; return v.u;
}

DEV f32x4 mfma16x16x32(bf16x8 a, bf16x8 b, f32x4 c) {
  return __builtin_amdgcn_mfma_f32_16x16x32_bf16(a, b, c, 0, 0, 0);
}

DEV void glds16(const void* g, void* l) {
  __builtin_amdgcn_global_load_lds(
      (__attribute__((address_space(1))) void*)(uintptr_t)(g),
      (__attribute__((address_space(3))) void*)(l), 16, 0, 0);
}

#define B_   2
#define N_   2048
#define DIM_ 1024
#define H_   16
#define DH_  64
#define BH_  (B_ * H_)
#define BN_  (B_ * N_)

// ---------------------------------------------------------------------------
// 1) cos/sin table: cs[(n*32+j)*2] = cos(n * 10000^(-2j/64)), +1 = sin
// ---------------------------------------------------------------------------
__global__ void cs_kernel(float* __restrict__ cs) {
  int tid = blockIdx.x * blockDim.x + threadIdx.x;   // 65536 = 2048 * 32
  int n = tid >> 5, j = tid & 31;
  float inv = powf(10000.0f, -(float)(2 * j) / 64.0f);
  float ang = (float)n * inv;
  cs[2 * tid]     = cosf(ang);
  cs[2 * tid + 1] = sinf(ang);
}

// ---------------------------------------------------------------------------
// 2) fp32 -> bf16 elementwise (for x)
// ---------------------------------------------------------------------------
__global__ __launch_bounds__(256) void conv_kernel(const float* __restrict__ src,
                                                   short* __restrict__ dst) {
  int i = (blockIdx.x * 256 + threadIdx.x) * 8;
  float4 a = *(const float4*)(src + i);
  float4 b = *(const float4*)(src + i + 4);
  bf16x8 o;
  o[0] = f2bf(a.x); o[1] = f2bf(a.y); o[2] = f2bf(a.z); o[3] = f2bf(a.w);
  o[4] = f2bf(b.x); o[5] = f2bf(b.y); o[6] = f2bf(b.z); o[7] = f2bf(b.w);
  *(bf16x8*)(dst + i) = o;
}

// ---------------------------------------------------------------------------
// 3) transpose fp32 [R][C] -> bf16 [C][R]  (64x64 LDS tiles)
//    PERM: for q/k thirds (cb < 2048) write row cb + pi(cl):
//    pi(d): j=d>>1, s=d&1 -> 32*(j>>4) + 16*s + (j&15). RoPE pairs land in
//    the SAME lane of the GEMM C-fragment (ni pairs).
// ---------------------------------------------------------------------------
template <bool PERM>
__global__ __launch_bounds__(256) void transw_kernel(const float* __restrict__ src,
                                                     short* __restrict__ dst,
                                                     int R, int C) {
  __shared__ unsigned short lds[64 * 65];
  const int t = threadIdx.x;
  const int cb = blockIdx.x * 64, rb = blockIdx.y * 64;
  #pragma unroll
  for (int pass = 0; pass < 4; ++pass) {
    int r  = pass * 16 + (t >> 4);
    int cc = (t & 15) * 4;
    float4 v = *(const float4*)(src + (size_t)(rb + r) * C + cb + cc);
    lds[(cc + 0) * 65 + r] = (unsigned short)f2bf(v.x);
    lds[(cc + 1) * 65 + r] = (unsigned short)f2bf(v.y);
    lds[(cc + 2) * 65 + r] = (unsigned short)f2bf(v.z);
    lds[(cc + 3) * 65 + r] = (unsigned short)f2bf(v.w);
  }
  __syncthreads();
  const int cl = t >> 2, chunk = t & 3;
  bf16x8 o0, o1;
  #pragma unroll
  for (int j = 0; j < 8; ++j) {
    o0[j] = (short)lds[cl * 65 + chunk * 16 + j];
    o1[j] = (short)lds[cl * 65 + chunk * 16 + 8 + j];
  }
  int ocl = cl;
  if (PERM && cb < 2048) {
    int j = cl >> 1, s2 = cl & 1;
    ocl = ((j >> 4) << 5) + (s2 << 4) + (j & 15);
  }
  size_t off = (size_t)(cb + ocl) * R + rb + chunk * 16;
  *(bf16x8*)(dst + off)     = o0;
  *(bf16x8*)(dst + off + 8) = o1;
}

// ---------------------------------------------------------------------------
// 4) GEMM: C = A @ BT^T. 128x128 tile, BK=64, chunk-XOR swizzled glds source
//    (r10-proven). MODE 0: f32 output. MODE 2: fused QKV epilogue —
//    q/k thirds: lane-local RoPE on f32 acc (perm'd W cols) -> qb/kb;
//    v third: transposed write -> vT. Bijective XCD swizzle (nwg%8==0).
// ---------------------------------------------------------------------------
template <int MODE>
__global__ __launch_bounds__(256) void gemm_bt_kernel(const short* __restrict__ A,
                                                      const short* __restrict__ BT,
                                                      float* __restrict__ Cout,
                                                      short* __restrict__ qb,
                                                      short* __restrict__ kb,
                                                      short* __restrict__ vT,
                                                      const float* __restrict__ cs,
                                                      int M, int N, int K, int gx) {
  __shared__ short As[128 * 64];
  __shared__ short Bs[128 * 64];
  const int nwg = gridDim.x;
  const int bid = blockIdx.x;
  const int swz = (bid & 7) * (nwg >> 3) + (bid >> 3);  // bijective: nwg%8==0
  const int bx = swz % gx, by = swz / gx;
  const int t = threadIdx.x;
  const int lane = t & 63, w = t >> 6;
  const int c = lane & 15, g = lane >> 4;
  const int wm = w >> 1, wn = w & 1;
  const int mbase = by * 128, nbase = bx * 128;
  const short* Ab = A + (size_t)mbase * K;
  const short* Bb = BT + (size_t)nbase * K;
  f32x4 acc[4][4] = {};
  for (int kb2 = 0; kb2 < K; kb2 += 64) {
    #pragma unroll
    for (int i = 0; i < 4; ++i) {
      const int idx = i * 256 + t;             // 0..1023 chunk id
      const int row = idx >> 3, p = idx & 7;
      const int gc = ((p ^ (row & 7)) << 3);   // source chunk pre-swizzle
      glds16(Ab + (size_t)row * K + kb2 + gc, As + idx * 8);
      glds16(Bb + (size_t)row * K + kb2 + gc, Bs + idx * 8);
    }
    __syncthreads();
    bf16x8 af[4][2], bfr[4][2];
    #pragma unroll
    for (int mi = 0; mi < 4; ++mi) {
      const int r = wm * 64 + mi * 16 + c;
      #pragma unroll
      for (int kk = 0; kk < 2; ++kk)
        af[mi][kk] = *(const bf16x8*)&As[r * 64 + (((kk * 4 + g) ^ (r & 7)) << 3)];
    }
    #pragma unroll
    for (int ni = 0; ni < 4; ++ni) {
      const int r = wn * 64 + ni * 16 + c;
      #pragma unroll
      for (int kk = 0; kk < 2; ++kk)
        bfr[ni][kk] = *(const bf16x8*)&Bs[r * 64 + (((kk * 4 + g) ^ (r & 7)) << 3)];
    }
    #pragma unroll
    for (int kk = 0; kk < 2; ++kk)
      #pragma unroll
      for (int mi = 0; mi < 4; ++mi)
        #pragma unroll
        for (int ni = 0; ni < 4; ++ni)
          acc[mi][ni] = mfma16x16x32(af[mi][kk], bfr[ni][kk], acc[mi][ni]);
    __syncthreads();
  }
  if constexpr (MODE == 0) {
    #pragma unroll
    for (int mi = 0; mi < 4; ++mi) {
      const int row = mbase + wm * 64 + mi * 16 + g * 4;
      #pragma unroll
      for (int ni = 0; ni < 4; ++ni) {
        const int col = nbase + wn * 64 + ni * 16 + c;
        #pragma unroll
        for (int r = 0; r < 4; ++r)
          Cout[(size_t)(row + r) * N + col] = acc[mi][ni][r];
      }
    }
  } else {
    const int col0 = nbase + wn * 64;     // head base; one head per warp
    const int i3 = col0 >> 10;            // 0=q, 1=k, 2=v
    const int h  = (col0 >> 6) & 15;
    if (i3 < 2) {
      // lane c holds logical d pairs: (2c,2c+1) at ni=0,1 ; (2c+32,2c+33) at ni=2,3
      short* dst0 = (i3 == 0) ? qb : kb;
      const float sc = (i3 == 0) ? 0.125f : 1.0f;
      #pragma unroll
      for (int mi = 0; mi < 4; ++mi) {
        const int row0 = mbase + wm * 64 + mi * 16 + g * 4;
        #pragma unroll
        for (int r = 0; r < 4; ++r) {
          const int row = row0 + r;
          const int n = row & 2047, b = row >> 11;
          short* dp = dst0 + ((size_t)(b * H_ + h) * N_ + n) * DH_;
          float2 cs0 = ((const float2*)cs)[n * 32 + c];
          float2 cs1 = ((const float2*)cs)[n * 32 + c + 16];
          float t1 = acc[mi][0][r], t2 = acc[mi][1][r];
          float t3 = acc[mi][2][r], t4 = acc[mi][3][r];
          unsigned u0 = packbf((t1 * cs0.x - t2 * cs0.y) * sc,
                               (t1 * cs0.y + t2 * cs0.x) * sc);
          unsigned u1 = packbf((t3 * cs1.x - t4 * cs1.y) * sc,
                               (t3 * cs1.y + t4 * cs1.x) * sc);
          *(unsigned*)(dp + 2 * c)      = u0;   // d = 2c, 2c+1
          *(unsigned*)(dp + 32 + 2 * c) = u1;   // d = 2c+32, 2c+33
        }
      }
    } else {
      // V: write transposed directly: vT[bh][d][n]
      #pragma unroll
      for (int mi = 0; mi < 4; ++mi) {
        const int row0 = mbase + wm * 64 + mi * 16 + g * 4;
        const int n0 = row0 & 2047, b = row0 >> 11;
        const int bh = b * H_ + h;
        #pragma unroll
        for (int ni = 0; ni < 4; ++ni) {
          const int dd = ni * 16 + c;
          bf16x4 ov;
          #pragma unroll
          for (int r = 0; r < 4; ++r) ov[r] = f2bf(acc[mi][ni][r]);
          *(bf16x4*)(vT + ((size_t)bh * DH_ + dd) * N_ + n0) = ov;
        }
      }
    }
  }
}

// ---------------------------------------------------------------------------
// 7) Flash attention — r14 GREEN form (measured local optimum). 512 blocks,
//    128 q-rows/block, 4 waves, KVBLK=64, reg-staged dbuf LDS, exact-skip
//    rescale, tree sum, packbf, setprio, XCD-grouped grid.
// ---------------------------------------------------------------------------
__global__ __launch_bounds__(256) void attn_kernel(const short* __restrict__ qb,
                                                   const short* __restrict__ kb,
                                                   const short* __restrict__ vT,
                                                   short* __restrict__ attn_out) {
  __shared__ short Kt[2][4096];   // 8 KB per buf: [row 0..63][chunk 0..7][8]
  __shared__ short Vt[2][4096];
  const int t = threadIdx.x;
  const int lane = t & 63, w = t >> 6;
  const int c = lane & 15, g = lane >> 4;
  const int bid = blockIdx.x;               // 512 blocks, 1D
  const int xcd = bid & 7, slot = bid >> 3; // slot 0..63
  const int bh = xcd + ((slot >> 4) << 3);  // 16 x-blocks of bh share an XCD
  const int xb = slot & 15;
  const int qbase = xb * 128 + w * 32;
  const short* kbase = kb + (size_t)bh * N_ * DH_;
  const short* vbase = vT + (size_t)bh * DH_ * N_;

  // staging map (per thread, 2 chunks per array): ch = j*256+t
  const int s_row0 = t >> 3,          s_p0 = t & 7;
  const int s_row1 = (256 + t) >> 3,  s_p1 = t & 7;   // rows 32..63
  const int s_dst0 = s_row0 * 64 + ((s_p0 ^ (s_row0 & 7)) << 3);
  const int s_dst1 = s_row1 * 64 + ((s_p1 ^ (s_row1 & 7)) << 3);

  // Q fragments held in registers for the whole kv loop; q pre-scaled 1/8
  bf16x8 qlo[2], qhi[2];
  #pragma unroll
  for (int qf = 0; qf < 2; ++qf) {
    const short* qp = qb + ((size_t)bh * N_ + qbase + qf * 16 + c) * DH_;
    qlo[qf] = *(const bf16x8*)(qp + g * 8);
    qhi[qf] = *(const bf16x8*)(qp + 32 + g * 8);
  }

  float M[2] = {-INFINITY, -INFINITY};
  float L[2] = {0.f, 0.f};
  f32x4 o[4][2] = {};
  bf16x8 kr0, kr1, vr0, vr1;

  // prologue: load tile 0 -> regs, write buf 0, barrier
  kr0 = *(const bf16x8*)(kbase + (size_t)s_row0 * DH_ + s_p0 * 8);
  kr1 = *(const bf16x8*)(kbase + (size_t)s_row1 * DH_ + s_p1 * 8);
  vr0 = *(const bf16x8*)(vbase + (size_t)s_row0 * N_ + s_p0 * 8);
  vr1 = *(const bf16x8*)(vbase + (size_t)s_row1 * N_ + s_p1 * 8);
  *(bf16x8*)(&Kt[0][s_dst0]) = kr0;
  *(bf16x8*)(&Kt[0][s_dst1]) = kr1;
  *(bf16x8*)(&Vt[0][s_dst0]) = vr0;
  *(bf16x8*)(&Vt[0][s_dst1]) = vr1;
  __syncthreads();

  for (int it = 0; it < 32; ++it) {
    const int cur = it & 1;
    const int pf_valid = (it + 1 < 32);
    if (pf_valid) {  // issue next-tile loads BEFORE compute (overlap)
      const int kv = (it + 1) * 64;
      kr0 = *(const bf16x8*)(kbase + (size_t)(kv + s_row0) * DH_ + s_p0 * 8);
      kr1 = *(const bf16x8*)(kbase + (size_t)(kv + s_row1) * DH_ + s_p1 * 8);
      vr0 = *(const bf16x8*)(vbase + (size_t)s_row0 * N_ + kv + s_p0 * 8);
      vr1 = *(const bf16x8*)(vbase + (size_t)s_row1 * N_ + kv + s_p1 * 8);
    }
    // --- QK^T: s lane holds S[q=qf*16+c][j=it*64+jt*16+g*4+r] ---
    f32x4 s[4][2] = {};
    __builtin_amdgcn_s_setprio(1);
    #pragma unroll
    for (int jt = 0; jt < 4; ++jt) {
      const int r_ = jt * 16 + c;
      const short* kt = &Kt[cur][r_ * 64];
      bf16x8 k0 = *(const bf16x8*)(kt + ((g ^ (r_ & 7)) << 3));
      bf16x8 k1 = *(const bf16x8*)(kt + (((g + 4) ^ (r_ & 7)) << 3));
      #pragma unroll
      for (int qf = 0; qf < 2; ++qf) {
        s[jt][qf] = mfma16x16x32(k0, qlo[qf], s[jt][qf]);
        s[jt][qf] = mfma16x16x32(k1, qhi[qf], s[jt][qf]);
      }
    }
    __builtin_amdgcn_s_setprio(0);
    // --- online softmax: exact-skip rescale + tree sum ---
    bf16x8 pf[2][2];
    #pragma unroll
    for (int qf = 0; qf < 2; ++qf) {
      float m0 = fmaxf(fmaxf(s[0][qf][0], s[0][qf][1]), s[0][qf][2]);
      float m1 = fmaxf(fmaxf(s[0][qf][3], s[1][qf][0]), s[1][qf][1]);
      float m2 = fmaxf(fmaxf(s[1][qf][2], s[1][qf][3]), s[2][qf][0]);
      float m3 = fmaxf(fmaxf(s[2][qf][1], s[2][qf][2]), s[2][qf][3]);
      float m4 = fmaxf(fmaxf(s[3][qf][0], s[3][qf][1]), s[3][qf][2]);
      float mx = fmaxf(fmaxf(fmaxf(m0, m1), fmaxf(m2, m3)),
                       fmaxf(m4, s[3][qf][3]));
      mx = fmaxf(mx, __shfl_xor(mx, 16));
      mx = fmaxf(mx, __shfl_xor(mx, 32));
      if (__any(mx > M[qf])) {   // else corr==expf(0)==1 for all lanes: EXACT skip
        const float mnew = fmaxf(M[qf], mx);
        const float corr = __expf(M[qf] - mnew);  // exp(-inf)=0 first tile
        L[qf] *= corr;
        #pragma unroll
        for (int dt = 0; dt < 4; ++dt) o[dt][qf] *= corr;
        M[qf] = mnew;
      }
      #pragma unroll
      for (int jt = 0; jt < 4; ++jt)
        #pragma unroll
        for (int r = 0; r < 4; ++r)
          s[jt][qf][r] = __expf(s[jt][qf][r] - M[qf]);
      float t0 = (s[0][qf][0] + s[0][qf][1]) + (s[0][qf][2] + s[0][qf][3]);
      float t1 = (s[1][qf][0] + s[1][qf][1]) + (s[1][qf][2] + s[1][qf][3]);
      float t2 = (s[2][qf][0] + s[2][qf][1]) + (s[2][qf][2] + s[2][qf][3]);
      float t3 = (s[3][qf][0] + s[3][qf][1]) + (s[3][qf][2] + s[3][qf][3]);
      float rs = (t0 + t1) + (t2 + t3);
      rs += __shfl_xor(rs, 16);
      rs += __shfl_xor(rs, 32);
      L[qf] += rs;
      union { unsigned u[4]; bf16x8 v; } P0, P1;
      P0.u[0] = packbf(s[0][qf][0], s[0][qf][1]);
      P0.u[1] = packbf(s[0][qf][2], s[0][qf][3]);
      P0.u[2] = packbf(s[1][qf][0], s[1][qf][1]);
      P0.u[3] = packbf(s[1][qf][2], s[1][qf][3]);
      P1.u[0] = packbf(s[2][qf][0], s[2][qf][1]);
      P1.u[1] = packbf(s[2][qf][2], s[2][qf][3]);
      P1.u[2] = packbf(s[3][qf][0], s[3][qf][1]);
      P1.u[3] = packbf(s[3][qf][2], s[3][qf][3]);
      pf[qf][0] = P0.v;
      pf[qf][1] = P1.v;
    }
    // --- PV: A = V^T rows d, slot map j = kf*32 + (s<4 ? g*4+s : 16+g*4+s-4)
    __builtin_amdgcn_s_setprio(1);
    #pragma unroll
    for (int dt = 0; dt < 4; ++dt) {
      const int d = dt * 16 + c;
      const short* vt = &Vt[cur][d * 64];
      const int dx = d & 7;
      #pragma unroll
      for (int kf = 0; kf < 2; ++kf) {
        const int e0 = kf * 32 + g * 4;
        const int e1 = e0 + 16;
        bf16x4 a0 = *(const bf16x4*)(vt + ((((e0 >> 3) ^ dx) << 3) | (e0 & 7)));
        bf16x4 a1 = *(const bf16x4*)(vt + ((((e1 >> 3) ^ dx) << 3) | (e1 & 7)));
        bf16x8 vf = __builtin_shufflevector(a0, a1, 0, 1, 2, 3, 4, 5, 6, 7);
        o[dt][0] = mfma16x16x32(vf, pf[0][kf], o[dt][0]);
        o[dt][1] = mfma16x16x32(vf, pf[1][kf], o[dt][1]);
      }
    }
    __builtin_amdgcn_s_setprio(0);
    // --- write-late: store prefetched regs into the idle buffer ---
    if (pf_valid) {
      *(bf16x8*)(&Kt[cur ^ 1][s_dst0]) = kr0;
      *(bf16x8*)(&Kt[cur ^ 1][s_dst1]) = kr1;
      *(bf16x8*)(&Vt[cur ^ 1][s_dst0]) = vr0;
      *(bf16x8*)(&Vt[cur ^ 1][s_dst1]) = vr1;
    }
    __syncthreads();
  }

  const int b = bh >> 4, h = bh & 15;
  #pragma unroll
  for (int qf = 0; qf < 2; ++qf) {
    const float inv = 1.0f / L[qf];
    short* op = attn_out + ((size_t)b * N_ + qbase + qf * 16 + c) * (H_ * DH_) + h * DH_;
    #pragma unroll
    for (int dt = 0; dt < 4; ++dt) {
      bf16x4 ov;
      #pragma unroll
      for (int r = 0; r < 4; ++r) ov[r] = f2bf(o[dt][qf][r] * inv);
      *(bf16x4*)(op + dt * 16 + g * 4) = ov;
    }
  }
}

// ---------------------------------------------------------------------------
extern "C" void kernel_launch(void* const* d_in, const int* in_sizes, int n_in,
                              void* d_out, int out_size, void* d_ws, size_t ws_size,
                              hipStream_t stream) {
  const float* x    = (const float*)d_in[0];
  const float* Wqkv = (const float*)d_in[1];
  const float* Wout = (const float*)d_in[2];
  char* ws = (char*)d_ws;
  // workspace layout (MiB offsets)
  short* xb    = (short*)(ws);                        // 8 MiB  [4096][1024]
  short* WqkvT = (short*)(ws + ((size_t)8 << 20));    // 6 MiB  [3072][1024] (perm'd q/k cols)
  short* WoutT = (short*)(ws + ((size_t)14 << 20));   // 2 MiB  [1024][1024]
  short* qb    = (short*)(ws + ((size_t)40 << 20));   // 8 MiB  [32][2048][64]
  short* kb    = (short*)(ws + ((size_t)48 << 20));   // 8 MiB
  short* vT    = (short*)(ws + ((size_t)56 << 20));   // 8 MiB  [32][64][2048]
  short* attn  = (short*)(ws + ((size_t)64 << 20));   // 8 MiB  [4096][1024]
  float* cs    = (float*)(ws + ((size_t)72 << 20));   // 0.5 MiB [2048][32][2]

  cs_kernel<<<dim3(256), 256, 0, stream>>>(cs);
  conv_kernel<<<dim3(2048), 256, 0, stream>>>(x, xb);                              // x -> bf16
  transw_kernel<true><<<dim3(48, 16), 256, 0, stream>>>(Wqkv, WqkvT, 1024, 3072);  // Wqkv^T (perm)
  transw_kernel<false><<<dim3(16, 16), 256, 0, stream>>>(Wout, WoutT, 1024, 1024); // Wout^T
  // GEMM1 with fused RoPE + V-transpose epilogue (writes qb, kb, vT directly)
  gemm_bt_kernel<2><<<dim3(768), 256, 0, stream>>>(xb, WqkvT, nullptr, qb, kb, vT, cs,
                                                   4096, 3072, 1024, 24);
  attn_kernel<<<dim3(512), 256, 0, stream>>>(qb, kb, vT, attn);
  gemm_bt_kernel<0><<<dim3(256), 256, 0, stream>>>(attn, WoutT, (float*)d_out,
                                                   nullptr, nullptr, nullptr, nullptr,
                                                   4096, 1024, 1024, 8);
}

// Round 17
// 152.105 us; speedup vs baseline: 1.2178x; 1.0539x over previous
//
#include <hip/hip_runtime.h>
#include <hip/hip_bf16.h>
#include <stdint.h>
#include <math.h>

using bf16x8 = __attribute__((ext_vector_type(8))) short;
using bf16x4 = __attribute__((ext_vector_type(4))) short;
using f32x4  = __attribute__((ext_vector_type(4))) float;

#define DEV static __device__ __forceinline__

// SESSION LEDGER:
//  - r6/7: v_cvt_pk_bf16_f32 INLINE ASM => NaN. BANNED. packbf (compiler) green.
//  - r4/r12: exp2-domain q-prescale => absmax 5.86e-3 (deterministic). BANNED.
//    q prescale stays EXACT POW2 (0.125) + __expf.
//  - attn design-space: r8 Q-split REGRESS (2x staging), r11 KV-split NULL,
//    r13 chain-cuts NULL, r15 KVBLK=128 REGRESS (occupancy). r14 form best.
//  - r10: BK=64 swizzled-glds GEMM green. If unexplained NaN: revert to BK=32.
//  - r14: RoPE+V-transpose fused into GEMM1 epilogue (green, bit-stable).
//  - r17 (this): attn 8 waves/block, 256 q-rows (r8 inverted): K/V staged
//    once for 8 waves -> per-thread staging halves, FETCH halves; per-wave
//    compute bit-identical; same 8 waves/CU residency. If regress: r16 anchor.

DEV float bf2f(short s) {
  union { unsigned u; float f; } v; v.u = ((unsigned)(unsigned short)s) << 16; return v.f;
}
DEV short f2bf(float f) {
  union { float ff; unsigned u; } v; v.ff = f;
  unsigned r = v.u + 0x7fffu + ((v.u >> 16) & 1u);
  return (short)(r >> 16);
}
DEV unsigned packbf(float a, float b) {  // lo16 = RNE(a), hi16 = RNE(b)
  __hip_bfloat162 h = __float22bfloat162_rn(make_float2(a, b));
  union { __hip_bfloat162 h2; unsigned u; } v; v.h2 = h; return v.u;
}

DEV f32x4 mfma16x16x32(bf16x8 a, bf16x8 b, f32x4 c) {
  return __builtin_amdgcn_mfma_f32_16x16x32_bf16(a, b, c, 0, 0, 0);
}

DEV void glds16(const void* g, void* l) {
  __builtin_amdgcn_global_load_lds(
      (__attribute__((address_space(1))) void*)(uintptr_t)(g),
      (__attribute__((address_space(3))) void*)(l), 16, 0, 0);
}

#define B_   2
#define N_   2048
#define DIM_ 1024
#define H_   16
#define DH_  64
#define BH_  (B_ * H_)
#define BN_  (B_ * N_)

// ---------------------------------------------------------------------------
// 1) cos/sin table: cs[(n*32+j)*2] = cos(n * 10000^(-2j/64)), +1 = sin
// ---------------------------------------------------------------------------
__global__ void cs_kernel(float* __restrict__ cs) {
  int tid = blockIdx.x * blockDim.x + threadIdx.x;   // 65536 = 2048 * 32
  int n = tid >> 5, j = tid & 31;
  float inv = powf(10000.0f, -(float)(2 * j) / 64.0f);
  float ang = (float)n * inv;
  cs[2 * tid]     = cosf(ang);
  cs[2 * tid + 1] = sinf(ang);
}

// ---------------------------------------------------------------------------
// 2) fp32 -> bf16 elementwise (for x)
// ---------------------------------------------------------------------------
__global__ __launch_bounds__(256) void conv_kernel(const float* __restrict__ src,
                                                   short* __restrict__ dst) {
  int i = (blockIdx.x * 256 + threadIdx.x) * 8;
  float4 a = *(const float4*)(src + i);
  float4 b = *(const float4*)(src + i + 4);
  bf16x8 o;
  o[0] = f2bf(a.x); o[1] = f2bf(a.y); o[2] = f2bf(a.z); o[3] = f2bf(a.w);
  o[4] = f2bf(b.x); o[5] = f2bf(b.y); o[6] = f2bf(b.z); o[7] = f2bf(b.w);
  *(bf16x8*)(dst + i) = o;
}

// ---------------------------------------------------------------------------
// 3) transpose fp32 [R][C] -> bf16 [C][R]  (64x64 LDS tiles)
//    PERM: for q/k thirds (cb < 2048) write row cb + pi(cl):
//    pi(d): j=d>>1, s=d&1 -> 32*(j>>4) + 16*s + (j&15). RoPE pairs land in
//    the SAME lane of the GEMM C-fragment (ni pairs).
// ---------------------------------------------------------------------------
template <bool PERM>
__global__ __launch_bounds__(256) void transw_kernel(const float* __restrict__ src,
                                                     short* __restrict__ dst,
                                                     int R, int C) {
  __shared__ unsigned short lds[64 * 65];
  const int t = threadIdx.x;
  const int cb = blockIdx.x * 64, rb = blockIdx.y * 64;
  #pragma unroll
  for (int pass = 0; pass < 4; ++pass) {
    int r  = pass * 16 + (t >> 4);
    int cc = (t & 15) * 4;
    float4 v = *(const float4*)(src + (size_t)(rb + r) * C + cb + cc);
    lds[(cc + 0) * 65 + r] = (unsigned short)f2bf(v.x);
    lds[(cc + 1) * 65 + r] = (unsigned short)f2bf(v.y);
    lds[(cc + 2) * 65 + r] = (unsigned short)f2bf(v.z);
    lds[(cc + 3) * 65 + r] = (unsigned short)f2bf(v.w);
  }
  __syncthreads();
  const int cl = t >> 2, chunk = t & 3;
  bf16x8 o0, o1;
  #pragma unroll
  for (int j = 0; j < 8; ++j) {
    o0[j] = (short)lds[cl * 65 + chunk * 16 + j];
    o1[j] = (short)lds[cl * 65 + chunk * 16 + 8 + j];
  }
  int ocl = cl;
  if (PERM && cb < 2048) {
    int j = cl >> 1, s2 = cl & 1;
    ocl = ((j >> 4) << 5) + (s2 << 4) + (j & 15);
  }
  size_t off = (size_t)(cb + ocl) * R + rb + chunk * 16;
  *(bf16x8*)(dst + off)     = o0;
  *(bf16x8*)(dst + off + 8) = o1;
}

// ---------------------------------------------------------------------------
// 4) GEMM: C = A @ BT^T. 128x128 tile, BK=64, chunk-XOR swizzled glds source
//    (r10-proven). MODE 0: f32 output. MODE 2: fused QKV epilogue —
//    q/k thirds: lane-local RoPE on f32 acc (perm'd W cols) -> qb/kb;
//    v third: transposed write -> vT. Bijective XCD swizzle (nwg%8==0).
// ---------------------------------------------------------------------------
template <int MODE>
__global__ __launch_bounds__(256) void gemm_bt_kernel(const short* __restrict__ A,
                                                      const short* __restrict__ BT,
                                                      float* __restrict__ Cout,
                                                      short* __restrict__ qb,
                                                      short* __restrict__ kb,
                                                      short* __restrict__ vT,
                                                      const float* __restrict__ cs,
                                                      int M, int N, int K, int gx) {
  __shared__ short As[128 * 64];
  __shared__ short Bs[128 * 64];
  const int nwg = gridDim.x;
  const int bid = blockIdx.x;
  const int swz = (bid & 7) * (nwg >> 3) + (bid >> 3);  // bijective: nwg%8==0
  const int bx = swz % gx, by = swz / gx;
  const int t = threadIdx.x;
  const int lane = t & 63, w = t >> 6;
  const int c = lane & 15, g = lane >> 4;
  const int wm = w >> 1, wn = w & 1;
  const int mbase = by * 128, nbase = bx * 128;
  const short* Ab = A + (size_t)mbase * K;
  const short* Bb = BT + (size_t)nbase * K;
  f32x4 acc[4][4] = {};
  for (int kb2 = 0; kb2 < K; kb2 += 64) {
    #pragma unroll
    for (int i = 0; i < 4; ++i) {
      const int idx = i * 256 + t;             // 0..1023 chunk id
      const int row = idx >> 3, p = idx & 7;
      const int gc = ((p ^ (row & 7)) << 3);   // source chunk pre-swizzle
      glds16(Ab + (size_t)row * K + kb2 + gc, As + idx * 8);
      glds16(Bb + (size_t)row * K + kb2 + gc, Bs + idx * 8);
    }
    __syncthreads();
    bf16x8 af[4][2], bfr[4][2];
    #pragma unroll
    for (int mi = 0; mi < 4; ++mi) {
      const int r = wm * 64 + mi * 16 + c;
      #pragma unroll
      for (int kk = 0; kk < 2; ++kk)
        af[mi][kk] = *(const bf16x8*)&As[r * 64 + (((kk * 4 + g) ^ (r & 7)) << 3)];
    }
    #pragma unroll
    for (int ni = 0; ni < 4; ++ni) {
      const int r = wn * 64 + ni * 16 + c;
      #pragma unroll
      for (int kk = 0; kk < 2; ++kk)
        bfr[ni][kk] = *(const bf16x8*)&Bs[r * 64 + (((kk * 4 + g) ^ (r & 7)) << 3)];
    }
    #pragma unroll
    for (int kk = 0; kk < 2; ++kk)
      #pragma unroll
      for (int mi = 0; mi < 4; ++mi)
        #pragma unroll
        for (int ni = 0; ni < 4; ++ni)
          acc[mi][ni] = mfma16x16x32(af[mi][kk], bfr[ni][kk], acc[mi][ni]);
    __syncthreads();
  }
  if constexpr (MODE == 0) {
    #pragma unroll
    for (int mi = 0; mi < 4; ++mi) {
      const int row = mbase + wm * 64 + mi * 16 + g * 4;
      #pragma unroll
      for (int ni = 0; ni < 4; ++ni) {
        const int col = nbase + wn * 64 + ni * 16 + c;
        #pragma unroll
        for (int r = 0; r < 4; ++r)
          Cout[(size_t)(row + r) * N + col] = acc[mi][ni][r];
      }
    }
  } else {
    const int col0 = nbase + wn * 64;     // head base; one head per warp
    const int i3 = col0 >> 10;            // 0=q, 1=k, 2=v
    const int h  = (col0 >> 6) & 15;
    if (i3 < 2) {
      // lane c holds logical d pairs: (2c,2c+1) at ni=0,1 ; (2c+32,2c+33) at ni=2,3
      short* dst0 = (i3 == 0) ? qb : kb;
      const float sc = (i3 == 0) ? 0.125f : 1.0f;
      #pragma unroll
      for (int mi = 0; mi < 4; ++mi) {
        const int row0 = mbase + wm * 64 + mi * 16 + g * 4;
        #pragma unroll
        for (int r = 0; r < 4; ++r) {
          const int row = row0 + r;
          const int n = row & 2047, b = row >> 11;
          short* dp = dst0 + ((size_t)(b * H_ + h) * N_ + n) * DH_;
          float2 cs0 = ((const float2*)cs)[n * 32 + c];
          float2 cs1 = ((const float2*)cs)[n * 32 + c + 16];
          float t1 = acc[mi][0][r], t2 = acc[mi][1][r];
          float t3 = acc[mi][2][r], t4 = acc[mi][3][r];
          unsigned u0 = packbf((t1 * cs0.x - t2 * cs0.y) * sc,
                               (t1 * cs0.y + t2 * cs0.x) * sc);
          unsigned u1 = packbf((t3 * cs1.x - t4 * cs1.y) * sc,
                               (t3 * cs1.y + t4 * cs1.x) * sc);
          *(unsigned*)(dp + 2 * c)      = u0;   // d = 2c, 2c+1
          *(unsigned*)(dp + 32 + 2 * c) = u1;   // d = 2c+32, 2c+33
        }
      }
    } else {
      // V: write transposed directly: vT[bh][d][n]
      #pragma unroll
      for (int mi = 0; mi < 4; ++mi) {
        const int row0 = mbase + wm * 64 + mi * 16 + g * 4;
        const int n0 = row0 & 2047, b = row0 >> 11;
        const int bh = b * H_ + h;
        #pragma unroll
        for (int ni = 0; ni < 4; ++ni) {
          const int dd = ni * 16 + c;
          bf16x4 ov;
          #pragma unroll
          for (int r = 0; r < 4; ++r) ov[r] = f2bf(acc[mi][ni][r]);
          *(bf16x4*)(vT + ((size_t)bh * DH_ + dd) * N_ + n0) = ov;
        }
      }
    }
  }
}

// ---------------------------------------------------------------------------
// 7) Flash attention — 8 waves / 256 q-rows per block (r8 inverted: K/V tile
//    staged ONCE for 8 consumer waves; per-wave compute bit-identical to r14).
//    256 blocks = 1/CU, 8 waves/CU (same residency as r14's 2x4).
//    Staging: 1 chunk per thread per array (512 threads cover 512 chunks).
// ---------------------------------------------------------------------------
__global__ __launch_bounds__(512) void attn_kernel(const short* __restrict__ qb,
                                                   const short* __restrict__ kb,
                                                   const short* __restrict__ vT,
                                                   short* __restrict__ attn_out) {
  __shared__ short Kt[2][4096];   // 8 KB per buf: [row 0..63][chunk 0..7][8]
  __shared__ short Vt[2][4096];
  const int t = threadIdx.x;                // 0..511
  const int lane = t & 63, w = t >> 6;      // 8 waves
  const int c = lane & 15, g = lane >> 4;
  const int bid = blockIdx.x;               // 256 blocks, 1D
  const int xcd = bid & 7, slot = bid >> 3; // slot 0..31
  const int bh = xcd + ((slot >> 3) << 3);  // 8 q-blocks of bh share an XCD
  const int xb = slot & 7;
  const int qbase = xb * 256 + w * 32;
  const short* kbase = kb + (size_t)bh * N_ * DH_;
  const short* vbase = vT + (size_t)bh * DH_ * N_;

  // staging map: 1 chunk per thread per array (512 chunks total each)
  const int s_row = t >> 3, s_p = t & 7;
  const int s_dst = s_row * 64 + ((s_p ^ (s_row & 7)) << 3);

  // Q fragments held in registers for the whole kv loop; q pre-scaled 1/8
  bf16x8 qlo[2], qhi[2];
  #pragma unroll
  for (int qf = 0; qf < 2; ++qf) {
    const short* qp = qb + ((size_t)bh * N_ + qbase + qf * 16 + c) * DH_;
    qlo[qf] = *(const bf16x8*)(qp + g * 8);
    qhi[qf] = *(const bf16x8*)(qp + 32 + g * 8);
  }

  float M[2] = {-INFINITY, -INFINITY};
  float L[2] = {0.f, 0.f};
  f32x4 o[4][2] = {};
  bf16x8 kr, vr;

  // prologue: load tile 0 -> regs, write buf 0, barrier
  kr = *(const bf16x8*)(kbase + (size_t)s_row * DH_ + s_p * 8);
  vr = *(const bf16x8*)(vbase + (size_t)s_row * N_ + s_p * 8);
  *(bf16x8*)(&Kt[0][s_dst]) = kr;
  *(bf16x8*)(&Vt[0][s_dst]) = vr;
  __syncthreads();

  for (int it = 0; it < 32; ++it) {
    const int cur = it & 1;
    const int pf_valid = (it + 1 < 32);
    if (pf_valid) {  // issue next-tile loads BEFORE compute (overlap)
      const int kv = (it + 1) * 64;
      kr = *(const bf16x8*)(kbase + (size_t)(kv + s_row) * DH_ + s_p * 8);
      vr = *(const bf16x8*)(vbase + (size_t)s_row * N_ + kv + s_p * 8);
    }
    // --- QK^T: s lane holds S[q=qf*16+c][j=it*64+jt*16+g*4+r] ---
    f32x4 s[4][2] = {};
    __builtin_amdgcn_s_setprio(1);
    #pragma unroll
    for (int jt = 0; jt < 4; ++jt) {
      const int r_ = jt * 16 + c;
      const short* kt = &Kt[cur][r_ * 64];
      bf16x8 k0 = *(const bf16x8*)(kt + ((g ^ (r_ & 7)) << 3));
      bf16x8 k1 = *(const bf16x8*)(kt + (((g + 4) ^ (r_ & 7)) << 3));
      #pragma unroll
      for (int qf = 0; qf < 2; ++qf) {
        s[jt][qf] = mfma16x16x32(k0, qlo[qf], s[jt][qf]);
        s[jt][qf] = mfma16x16x32(k1, qhi[qf], s[jt][qf]);
      }
    }
    __builtin_amdgcn_s_setprio(0);
    // --- online softmax: exact-skip rescale + tree sum ---
    bf16x8 pf[2][2];
    #pragma unroll
    for (int qf = 0; qf < 2; ++qf) {
      float m0 = fmaxf(fmaxf(s[0][qf][0], s[0][qf][1]), s[0][qf][2]);
      float m1 = fmaxf(fmaxf(s[0][qf][3], s[1][qf][0]), s[1][qf][1]);
      float m2 = fmaxf(fmaxf(s[1][qf][2], s[1][qf][3]), s[2][qf][0]);
      float m3 = fmaxf(fmaxf(s[2][qf][1], s[2][qf][2]), s[2][qf][3]);
      float m4 = fmaxf(fmaxf(s[3][qf][0], s[3][qf][1]), s[3][qf][2]);
      float mx = fmaxf(fmaxf(fmaxf(m0, m1), fmaxf(m2, m3)),
                       fmaxf(m4, s[3][qf][3]));
      mx = fmaxf(mx, __shfl_xor(mx, 16));
      mx = fmaxf(mx, __shfl_xor(mx, 32));
      if (__any(mx > M[qf])) {   // else corr==expf(0)==1 for all lanes: EXACT skip
        const float mnew = fmaxf(M[qf], mx);
        const float corr = __expf(M[qf] - mnew);  // exp(-inf)=0 first tile
        L[qf] *= corr;
        #pragma unroll
        for (int dt = 0; dt < 4; ++dt) o[dt][qf] *= corr;
        M[qf] = mnew;
      }
      #pragma unroll
      for (int jt = 0; jt < 4; ++jt)
        #pragma unroll
        for (int r = 0; r < 4; ++r)
          s[jt][qf][r] = __expf(s[jt][qf][r] - M[qf]);
      float t0 = (s[0][qf][0] + s[0][qf][1]) + (s[0][qf][2] + s[0][qf][3]);
      float t1 = (s[1][qf][0] + s[1][qf][1]) + (s[1][qf][2] + s[1][qf][3]);
      float t2 = (s[2][qf][0] + s[2][qf][1]) + (s[2][qf][2] + s[2][qf][3]);
      float t3 = (s[3][qf][0] + s[3][qf][1]) + (s[3][qf][2] + s[3][qf][3]);
      float rs = (t0 + t1) + (t2 + t3);
      rs += __shfl_xor(rs, 16);
      rs += __shfl_xor(rs, 32);
      L[qf] += rs;
      union { unsigned u[4]; bf16x8 v; } P0, P1;
      P0.u[0] = packbf(s[0][qf][0], s[0][qf][1]);
      P0.u[1] = packbf(s[0][qf][2], s[0][qf][3]);
      P0.u[2] = packbf(s[1][qf][0], s[1][qf][1]);
      P0.u[3] = packbf(s[1][qf][2], s[1][qf][3]);
      P1.u[0] = packbf(s[2][qf][0], s[2][qf][1]);
      P1.u[1] = packbf(s[2][qf][2], s[2][qf][3]);
      P1.u[2] = packbf(s[3][qf][0], s[3][qf][1]);
      P1.u[3] = packbf(s[3][qf][2], s[3][qf][3]);
      pf[qf][0] = P0.v;
      pf[qf][1] = P1.v;
    }
    // --- PV: A = V^T rows d, slot map j = kf*32 + (s<4 ? g*4+s : 16+g*4+s-4)
    __builtin_amdgcn_s_setprio(1);
    #pragma unroll
    for (int dt = 0; dt < 4; ++dt) {
      const int d = dt * 16 + c;
      const short* vt = &Vt[cur][d * 64];
      const int dx = d & 7;
      #pragma unroll
      for (int kf = 0; kf < 2; ++kf) {
        const int e0 = kf * 32 + g * 4;
        const int e1 = e0 + 16;
        bf16x4 a0 = *(const bf16x4*)(vt + ((((e0 >> 3) ^ dx) << 3) | (e0 & 7)));
        bf16x4 a1 = *(const bf16x4*)(vt + ((((e1 >> 3) ^ dx) << 3) | (e1 & 7)));
        bf16x8 vf = __builtin_shufflevector(a0, a1, 0, 1, 2, 3, 4, 5, 6, 7);
        o[dt][0] = mfma16x16x32(vf, pf[0][kf], o[dt][0]);
        o[dt][1] = mfma16x16x32(vf, pf[1][kf], o[dt][1]);
      }
    }
    __builtin_amdgcn_s_setprio(0);
    // --- write-late: store prefetched regs into the idle buffer ---
    if (pf_valid) {
      *(bf16x8*)(&Kt[cur ^ 1][s_dst]) = kr;
      *(bf16x8*)(&Vt[cur ^ 1][s_dst]) = vr;
    }
    __syncthreads();
  }

  const int b = bh >> 4, h = bh & 15;
  #pragma unroll
  for (int qf = 0; qf < 2; ++qf) {
    const float inv = 1.0f / L[qf];
    short* op = attn_out + ((size_t)b * N_ + qbase + qf * 16 + c) * (H_ * DH_) + h * DH_;
    #pragma unroll
    for (int dt = 0; dt < 4; ++dt) {
      bf16x4 ov;
      #pragma unroll
      for (int r = 0; r < 4; ++r) ov[r] = f2bf(o[dt][qf][r] * inv);
      *(bf16x4*)(op + dt * 16 + g * 4) = ov;
    }
  }
}

// ---------------------------------------------------------------------------
extern "C" void kernel_launch(void* const* d_in, const int* in_sizes, int n_in,
                              void* d_out, int out_size, void* d_ws, size_t ws_size,
                              hipStream_t stream) {
  const float* x    = (const float*)d_in[0];
  const float* Wqkv = (const float*)d_in[1];
  const float* Wout = (const float*)d_in[2];
  char* ws = (char*)d_ws;
  // workspace layout (MiB offsets)
  short* xb    = (short*)(ws);                        // 8 MiB  [4096][1024]
  short* WqkvT = (short*)(ws + ((size_t)8 << 20));    // 6 MiB  [3072][1024] (perm'd q/k cols)
  short* WoutT = (short*)(ws + ((size_t)14 << 20));   // 2 MiB  [1024][1024]
  short* qb    = (short*)(ws + ((size_t)40 << 20));   // 8 MiB  [32][2048][64]
  short* kb    = (short*)(ws + ((size_t)48 << 20));   // 8 MiB
  short* vT    = (short*)(ws + ((size_t)56 << 20));   // 8 MiB  [32][64][2048]
  short* attn  = (short*)(ws + ((size_t)64 << 20));   // 8 MiB  [4096][1024]
  float* cs    = (float*)(ws + ((size_t)72 << 20));   // 0.5 MiB [2048][32][2]

  cs_kernel<<<dim3(256), 256, 0, stream>>>(cs);
  conv_kernel<<<dim3(2048), 256, 0, stream>>>(x, xb);                              // x -> bf16
  transw_kernel<true><<<dim3(48, 16), 256, 0, stream>>>(Wqkv, WqkvT, 1024, 3072);  // Wqkv^T (perm)
  transw_kernel<false><<<dim3(16, 16), 256, 0, stream>>>(Wout, WoutT, 1024, 1024); // Wout^T
  // GEMM1 with fused RoPE + V-transpose epilogue (writes qb, kb, vT directly)
  gemm_bt_kernel<2><<<dim3(768), 256, 0, stream>>>(xb, WqkvT, nullptr, qb, kb, vT, cs,
                                                   4096, 3072, 1024, 24);
  attn_kernel<<<dim3(256), 512, 0, stream>>>(qb, kb, vT, attn);
  gemm_bt_kernel<0><<<dim3(256), 256, 0, stream>>>(attn, WoutT, (float*)d_out,
                                                   nullptr, nullptr, nullptr, nullptr,
                                                   4096, 1024, 1024, 8);
}

// Round 18
// 140.532 us; speedup vs baseline: 1.3181x; 1.0823x over previous
//
#include <hip/hip_runtime.h>
#include <hip/hip_bf16.h>
#include <stdint.h>
#include <math.h>

using bf16x8 = __attribute__((ext_vector_type(8))) short;
using bf16x4 = __attribute__((ext_vector_type(4))) short;
using f32x4  = __attribute__((ext_vector_type(4))) float;

#define DEV static __device__ __forceinline__

// SESSION LEDGER:
//  - r6/7: v_cvt_pk_bf16_f32 INLINE ASM => NaN. BANNED. packbf (compiler) green.
//  - r4/r12: exp2-domain q-prescale => absmax 5.86e-3 (deterministic). BANNED.
//  - attn: r8 Q-split REGRESS, r11 KV-split NULL, r13 chain-cuts NULL,
//    r15 KVBLK=128 REGRESS, r17 8-wave merge WIN (82.8->72.9us: staging ops
//    were on the serial chain). attn r17 form is the keeper.
//  - r10: BK=64 swizzled-glds GEMM green (bit-identical).
//  - r14: RoPE+V-transpose fused into GEMM1 epilogue (green).
//  - r18 (this): GEMMs 256x128 tile / 8 waves (same amortization lever):
//    staging/output -25%, barriers/output halved, per-output accumulation
//    sequence identical => bit-identical C. If regress: r17 GEMM form.

DEV float bf2f(short s) {
  union { unsigned u; float f; } v; v.u = ((unsigned)(unsigned short)s) << 16; return v.f;
}
DEV short f2bf(float f) {
  union { float ff; unsigned u; } v; v.ff = f;
  unsigned r = v.u + 0x7fffu + ((v.u >> 16) & 1u);
  return (short)(r >> 16);
}
DEV unsigned packbf(float a, float b) {  // lo16 = RNE(a), hi16 = RNE(b)
  __hip_bfloat162 h = __float22bfloat162_rn(make_float2(a, b));
  union { __hip_bfloat162 h2; unsigned u; } v; v.h2 = h; return v.u;
}

DEV f32x4 mfma16x16x32(bf16x8 a, bf16x8 b, f32x4 c) {
  return __builtin_amdgcn_mfma_f32_16x16x32_bf16(a, b, c, 0, 0, 0);
}

DEV void glds16(const void* g, void* l) {
  __builtin_amdgcn_global_load_lds(
      (__attribute__((address_space(1))) void*)(uintptr_t)(g),
      (__attribute__((address_space(3))) void*)(l), 16, 0, 0);
}

#define B_   2
#define N_   2048
#define DIM_ 1024
#define H_   16
#define DH_  64
#define BH_  (B_ * H_)
#define BN_  (B_ * N_)

// ---------------------------------------------------------------------------
// 1) cos/sin table: cs[(n*32+j)*2] = cos(n * 10000^(-2j/64)), +1 = sin
// ---------------------------------------------------------------------------
__global__ void cs_kernel(float* __restrict__ cs) {
  int tid = blockIdx.x * blockDim.x + threadIdx.x;   // 65536 = 2048 * 32
  int n = tid >> 5, j = tid & 31;
  float inv = powf(10000.0f, -(float)(2 * j) / 64.0f);
  float ang = (float)n * inv;
  cs[2 * tid]     = cosf(ang);
  cs[2 * tid + 1] = sinf(ang);
}

// ---------------------------------------------------------------------------
// 2) fp32 -> bf16 elementwise (for x)
// ---------------------------------------------------------------------------
__global__ __launch_bounds__(256) void conv_kernel(const float* __restrict__ src,
                                                   short* __restrict__ dst) {
  int i = (blockIdx.x * 256 + threadIdx.x) * 8;
  float4 a = *(const float4*)(src + i);
  float4 b = *(const float4*)(src + i + 4);
  bf16x8 o;
  o[0] = f2bf(a.x); o[1] = f2bf(a.y); o[2] = f2bf(a.z); o[3] = f2bf(a.w);
  o[4] = f2bf(b.x); o[5] = f2bf(b.y); o[6] = f2bf(b.z); o[7] = f2bf(b.w);
  *(bf16x8*)(dst + i) = o;
}

// ---------------------------------------------------------------------------
// 3) transpose fp32 [R][C] -> bf16 [C][R]  (64x64 LDS tiles)
//    PERM: for q/k thirds (cb < 2048) write row cb + pi(cl):
//    pi(d): j=d>>1, s=d&1 -> 32*(j>>4) + 16*s + (j&15). RoPE pairs land in
//    the SAME lane of the GEMM C-fragment (ni pairs).
// ---------------------------------------------------------------------------
template <bool PERM>
__global__ __launch_bounds__(256) void transw_kernel(const float* __restrict__ src,
                                                     short* __restrict__ dst,
                                                     int R, int C) {
  __shared__ unsigned short lds[64 * 65];
  const int t = threadIdx.x;
  const int cb = blockIdx.x * 64, rb = blockIdx.y * 64;
  #pragma unroll
  for (int pass = 0; pass < 4; ++pass) {
    int r  = pass * 16 + (t >> 4);
    int cc = (t & 15) * 4;
    float4 v = *(const float4*)(src + (size_t)(rb + r) * C + cb + cc);
    lds[(cc + 0) * 65 + r] = (unsigned short)f2bf(v.x);
    lds[(cc + 1) * 65 + r] = (unsigned short)f2bf(v.y);
    lds[(cc + 2) * 65 + r] = (unsigned short)f2bf(v.z);
    lds[(cc + 3) * 65 + r] = (unsigned short)f2bf(v.w);
  }
  __syncthreads();
  const int cl = t >> 2, chunk = t & 3;
  bf16x8 o0, o1;
  #pragma unroll
  for (int j = 0; j < 8; ++j) {
    o0[j] = (short)lds[cl * 65 + chunk * 16 + j];
    o1[j] = (short)lds[cl * 65 + chunk * 16 + 8 + j];
  }
  int ocl = cl;
  if (PERM && cb < 2048) {
    int j = cl >> 1, s2 = cl & 1;
    ocl = ((j >> 4) << 5) + (s2 << 4) + (j & 15);
  }
  size_t off = (size_t)(cb + ocl) * R + rb + chunk * 16;
  *(bf16x8*)(dst + off)     = o0;
  *(bf16x8*)(dst + off + 8) = o1;
}

// ---------------------------------------------------------------------------
// 4) GEMM: C = A @ BT^T. 256x128 tile, BK=64, 8 waves (512 thr), chunk-XOR
//    swizzled glds source. Per-wave 64x64 quadrant: wm=w>>1 (0..3), wn=w&1.
//    Per-output accumulation sequence identical to 128x128 form => bit-same.
//    MODE 0: f32 output. MODE 2: fused QKV epilogue (RoPE via perm'd W cols
//    -> qb/kb; V transposed -> vT). Bijective XCD swizzle (nwg%8==0).
// ---------------------------------------------------------------------------
template <int MODE>
__global__ __launch_bounds__(512) void gemm_bt_kernel(const short* __restrict__ A,
                                                      const short* __restrict__ BT,
                                                      float* __restrict__ Cout,
                                                      short* __restrict__ qb,
                                                      short* __restrict__ kb,
                                                      short* __restrict__ vT,
                                                      const float* __restrict__ cs,
                                                      int M, int N, int K, int gx) {
  __shared__ short As[256 * 64];   // 32 KB
  __shared__ short Bs[128 * 64];   // 16 KB
  const int nwg = gridDim.x;
  const int bid = blockIdx.x;
  const int swz = (bid & 7) * (nwg >> 3) + (bid >> 3);  // bijective: nwg%8==0
  const int bx = swz % gx, by = swz / gx;
  const int t = threadIdx.x;                // 0..511
  const int lane = t & 63, w = t >> 6;      // 8 waves
  const int c = lane & 15, g = lane >> 4;
  const int wm = w >> 1, wn = w & 1;
  const int mbase = by * 256, nbase = bx * 128;
  const short* Ab = A + (size_t)mbase * K;
  const short* Bb = BT + (size_t)nbase * K;
  f32x4 acc[4][4] = {};
  for (int kb2 = 0; kb2 < K; kb2 += 64) {
    #pragma unroll
    for (int i = 0; i < 4; ++i) {            // A: 2048 chunks
      const int idx = i * 512 + t;
      const int row = idx >> 3, p = idx & 7;
      const int gc = ((p ^ (row & 7)) << 3);
      glds16(Ab + (size_t)row * K + kb2 + gc, As + idx * 8);
    }
    #pragma unroll
    for (int i = 0; i < 2; ++i) {            // B: 1024 chunks
      const int idx = i * 512 + t;
      const int row = idx >> 3, p = idx & 7;
      const int gc = ((p ^ (row & 7)) << 3);
      glds16(Bb + (size_t)row * K + kb2 + gc, Bs + idx * 8);
    }
    __syncthreads();
    bf16x8 af[4][2], bfr[4][2];
    #pragma unroll
    for (int mi = 0; mi < 4; ++mi) {
      const int r = wm * 64 + mi * 16 + c;   // 0..255
      #pragma unroll
      for (int kk = 0; kk < 2; ++kk)
        af[mi][kk] = *(const bf16x8*)&As[r * 64 + (((kk * 4 + g) ^ (r & 7)) << 3)];
    }
    #pragma unroll
    for (int ni = 0; ni < 4; ++ni) {
      const int r = wn * 64 + ni * 16 + c;   // 0..127
      #pragma unroll
      for (int kk = 0; kk < 2; ++kk)
        bfr[ni][kk] = *(const bf16x8*)&Bs[r * 64 + (((kk * 4 + g) ^ (r & 7)) << 3)];
    }
    #pragma unroll
    for (int kk = 0; kk < 2; ++kk)
      #pragma unroll
      for (int mi = 0; mi < 4; ++mi)
        #pragma unroll
        for (int ni = 0; ni < 4; ++ni)
          acc[mi][ni] = mfma16x16x32(af[mi][kk], bfr[ni][kk], acc[mi][ni]);
    __syncthreads();
  }
  if constexpr (MODE == 0) {
    #pragma unroll
    for (int mi = 0; mi < 4; ++mi) {
      const int row = mbase + wm * 64 + mi * 16 + g * 4;
      #pragma unroll
      for (int ni = 0; ni < 4; ++ni) {
        const int col = nbase + wn * 64 + ni * 16 + c;
        #pragma unroll
        for (int r = 0; r < 4; ++r)
          Cout[(size_t)(row + r) * N + col] = acc[mi][ni][r];
      }
    }
  } else {
    const int col0 = nbase + wn * 64;     // head base; one head per warp
    const int i3 = col0 >> 10;            // 0=q, 1=k, 2=v
    const int h  = (col0 >> 6) & 15;
    if (i3 < 2) {
      // lane c holds logical d pairs: (2c,2c+1) at ni=0,1 ; (2c+32,2c+33) at ni=2,3
      short* dst0 = (i3 == 0) ? qb : kb;
      const float sc = (i3 == 0) ? 0.125f : 1.0f;
      #pragma unroll
      for (int mi = 0; mi < 4; ++mi) {
        const int row0 = mbase + wm * 64 + mi * 16 + g * 4;
        #pragma unroll
        for (int r = 0; r < 4; ++r) {
          const int row = row0 + r;
          const int n = row & 2047, b = row >> 11;
          short* dp = dst0 + ((size_t)(b * H_ + h) * N_ + n) * DH_;
          float2 cs0 = ((const float2*)cs)[n * 32 + c];
          float2 cs1 = ((const float2*)cs)[n * 32 + c + 16];
          float t1 = acc[mi][0][r], t2 = acc[mi][1][r];
          float t3 = acc[mi][2][r], t4 = acc[mi][3][r];
          unsigned u0 = packbf((t1 * cs0.x - t2 * cs0.y) * sc,
                               (t1 * cs0.y + t2 * cs0.x) * sc);
          unsigned u1 = packbf((t3 * cs1.x - t4 * cs1.y) * sc,
                               (t3 * cs1.y + t4 * cs1.x) * sc);
          *(unsigned*)(dp + 2 * c)      = u0;   // d = 2c, 2c+1
          *(unsigned*)(dp + 32 + 2 * c) = u1;   // d = 2c+32, 2c+33
        }
      }
    } else {
      // V: write transposed directly: vT[bh][d][n]
      #pragma unroll
      for (int mi = 0; mi < 4; ++mi) {
        const int row0 = mbase + wm * 64 + mi * 16 + g * 4;
        const int n0 = row0 & 2047, b = row0 >> 11;
        const int bh = b * H_ + h;
        #pragma unroll
        for (int ni = 0; ni < 4; ++ni) {
          const int dd = ni * 16 + c;
          bf16x4 ov;
          #pragma unroll
          for (int r = 0; r < 4; ++r) ov[r] = f2bf(acc[mi][ni][r]);
          *(bf16x4*)(vT + ((size_t)bh * DH_ + dd) * N_ + n0) = ov;
        }
      }
    }
  }
}

// ---------------------------------------------------------------------------
// 7) Flash attention — r17 WIN form, UNCHANGED. 8 waves / 256 q-rows per
//    block; K/V staged once for 8 consumer waves; 256 blocks = 1/CU.
// ---------------------------------------------------------------------------
__global__ __launch_bounds__(512) void attn_kernel(const short* __restrict__ qb,
                                                   const short* __restrict__ kb,
                                                   const short* __restrict__ vT,
                                                   short* __restrict__ attn_out) {
  __shared__ short Kt[2][4096];   // 8 KB per buf: [row 0..63][chunk 0..7][8]
  __shared__ short Vt[2][4096];
  const int t = threadIdx.x;                // 0..511
  const int lane = t & 63, w = t >> 6;      // 8 waves
  const int c = lane & 15, g = lane >> 4;
  const int bid = blockIdx.x;               // 256 blocks, 1D
  const int xcd = bid & 7, slot = bid >> 3; // slot 0..31
  const int bh = xcd + ((slot >> 3) << 3);  // 8 q-blocks of bh share an XCD
  const int xb = slot & 7;
  const int qbase = xb * 256 + w * 32;
  const short* kbase = kb + (size_t)bh * N_ * DH_;
  const short* vbase = vT + (size_t)bh * DH_ * N_;

  // staging map: 1 chunk per thread per array (512 chunks total each)
  const int s_row = t >> 3, s_p = t & 7;
  const int s_dst = s_row * 64 + ((s_p ^ (s_row & 7)) << 3);

  // Q fragments held in registers for the whole kv loop; q pre-scaled 1/8
  bf16x8 qlo[2], qhi[2];
  #pragma unroll
  for (int qf = 0; qf < 2; ++qf) {
    const short* qp = qb + ((size_t)bh * N_ + qbase + qf * 16 + c) * DH_;
    qlo[qf] = *(const bf16x8*)(qp + g * 8);
    qhi[qf] = *(const bf16x8*)(qp + 32 + g * 8);
  }

  float M[2] = {-INFINITY, -INFINITY};
  float L[2] = {0.f, 0.f};
  f32x4 o[4][2] = {};
  bf16x8 kr, vr;

  // prologue: load tile 0 -> regs, write buf 0, barrier
  kr = *(const bf16x8*)(kbase + (size_t)s_row * DH_ + s_p * 8);
  vr = *(const bf16x8*)(vbase + (size_t)s_row * N_ + s_p * 8);
  *(bf16x8*)(&Kt[0][s_dst]) = kr;
  *(bf16x8*)(&Vt[0][s_dst]) = vr;
  __syncthreads();

  for (int it = 0; it < 32; ++it) {
    const int cur = it & 1;
    const int pf_valid = (it + 1 < 32);
    if (pf_valid) {  // issue next-tile loads BEFORE compute (overlap)
      const int kv = (it + 1) * 64;
      kr = *(const bf16x8*)(kbase + (size_t)(kv + s_row) * DH_ + s_p * 8);
      vr = *(const bf16x8*)(vbase + (size_t)s_row * N_ + kv + s_p * 8);
    }
    // --- QK^T: s lane holds S[q=qf*16+c][j=it*64+jt*16+g*4+r] ---
    f32x4 s[4][2] = {};
    __builtin_amdgcn_s_setprio(1);
    #pragma unroll
    for (int jt = 0; jt < 4; ++jt) {
      const int r_ = jt * 16 + c;
      const short* kt = &Kt[cur][r_ * 64];
      bf16x8 k0 = *(const bf16x8*)(kt + ((g ^ (r_ & 7)) << 3));
      bf16x8 k1 = *(const bf16x8*)(kt + (((g + 4) ^ (r_ & 7)) << 3));
      #pragma unroll
      for (int qf = 0; qf < 2; ++qf) {
        s[jt][qf] = mfma16x16x32(k0, qlo[qf], s[jt][qf]);
        s[jt][qf] = mfma16x16x32(k1, qhi[qf], s[jt][qf]);
      }
    }
    __builtin_amdgcn_s_setprio(0);
    // --- online softmax: exact-skip rescale + tree sum ---
    bf16x8 pf[2][2];
    #pragma unroll
    for (int qf = 0; qf < 2; ++qf) {
      float m0 = fmaxf(fmaxf(s[0][qf][0], s[0][qf][1]), s[0][qf][2]);
      float m1 = fmaxf(fmaxf(s[0][qf][3], s[1][qf][0]), s[1][qf][1]);
      float m2 = fmaxf(fmaxf(s[1][qf][2], s[1][qf][3]), s[2][qf][0]);
      float m3 = fmaxf(fmaxf(s[2][qf][1], s[2][qf][2]), s[2][qf][3]);
      float m4 = fmaxf(fmaxf(s[3][qf][0], s[3][qf][1]), s[3][qf][2]);
      float mx = fmaxf(fmaxf(fmaxf(m0, m1), fmaxf(m2, m3)),
                       fmaxf(m4, s[3][qf][3]));
      mx = fmaxf(mx, __shfl_xor(mx, 16));
      mx = fmaxf(mx, __shfl_xor(mx, 32));
      if (__any(mx > M[qf])) {   // else corr==expf(0)==1 for all lanes: EXACT skip
        const float mnew = fmaxf(M[qf], mx);
        const float corr = __expf(M[qf] - mnew);  // exp(-inf)=0 first tile
        L[qf] *= corr;
        #pragma unroll
        for (int dt = 0; dt < 4; ++dt) o[dt][qf] *= corr;
        M[qf] = mnew;
      }
      #pragma unroll
      for (int jt = 0; jt < 4; ++jt)
        #pragma unroll
        for (int r = 0; r < 4; ++r)
          s[jt][qf][r] = __expf(s[jt][qf][r] - M[qf]);
      float t0 = (s[0][qf][0] + s[0][qf][1]) + (s[0][qf][2] + s[0][qf][3]);
      float t1 = (s[1][qf][0] + s[1][qf][1]) + (s[1][qf][2] + s[1][qf][3]);
      float t2 = (s[2][qf][0] + s[2][qf][1]) + (s[2][qf][2] + s[2][qf][3]);
      float t3 = (s[3][qf][0] + s[3][qf][1]) + (s[3][qf][2] + s[3][qf][3]);
      float rs = (t0 + t1) + (t2 + t3);
      rs += __shfl_xor(rs, 16);
      rs += __shfl_xor(rs, 32);
      L[qf] += rs;
      union { unsigned u[4]; bf16x8 v; } P0, P1;
      P0.u[0] = packbf(s[0][qf][0], s[0][qf][1]);
      P0.u[1] = packbf(s[0][qf][2], s[0][qf][3]);
      P0.u[2] = packbf(s[1][qf][0], s[1][qf][1]);
      P0.u[3] = packbf(s[1][qf][2], s[1][qf][3]);
      P1.u[0] = packbf(s[2][qf][0], s[2][qf][1]);
      P1.u[1] = packbf(s[2][qf][2], s[2][qf][3]);
      P1.u[2] = packbf(s[3][qf][0], s[3][qf][1]);
      P1.u[3] = packbf(s[3][qf][2], s[3][qf][3]);
      pf[qf][0] = P0.v;
      pf[qf][1] = P1.v;
    }
    // --- PV: A = V^T rows d, slot map j = kf*32 + (s<4 ? g*4+s : 16+g*4+s-4)
    __builtin_amdgcn_s_setprio(1);
    #pragma unroll
    for (int dt = 0; dt < 4; ++dt) {
      const int d = dt * 16 + c;
      const short* vt = &Vt[cur][d * 64];
      const int dx = d & 7;
      #pragma unroll
      for (int kf = 0; kf < 2; ++kf) {
        const int e0 = kf * 32 + g * 4;
        const int e1 = e0 + 16;
        bf16x4 a0 = *(const bf16x4*)(vt + ((((e0 >> 3) ^ dx) << 3) | (e0 & 7)));
        bf16x4 a1 = *(const bf16x4*)(vt + ((((e1 >> 3) ^ dx) << 3) | (e1 & 7)));
        bf16x8 vf = __builtin_shufflevector(a0, a1, 0, 1, 2, 3, 4, 5, 6, 7);
        o[dt][0] = mfma16x16x32(vf, pf[0][kf], o[dt][0]);
        o[dt][1] = mfma16x16x32(vf, pf[1][kf], o[dt][1]);
      }
    }
    __builtin_amdgcn_s_setprio(0);
    // --- write-late: store prefetched regs into the idle buffer ---
    if (pf_valid) {
      *(bf16x8*)(&Kt[cur ^ 1][s_dst]) = kr;
      *(bf16x8*)(&Vt[cur ^ 1][s_dst]) = vr;
    }
    __syncthreads();
  }

  const int b = bh >> 4, h = bh & 15;
  #pragma unroll
  for (int qf = 0; qf < 2; ++qf) {
    const float inv = 1.0f / L[qf];
    short* op = attn_out + ((size_t)b * N_ + qbase + qf * 16 + c) * (H_ * DH_) + h * DH_;
    #pragma unroll
    for (int dt = 0; dt < 4; ++dt) {
      bf16x4 ov;
      #pragma unroll
      for (int r = 0; r < 4; ++r) ov[r] = f2bf(o[dt][qf][r] * inv);
      *(bf16x4*)(op + dt * 16 + g * 4) = ov;
    }
  }
}

// ---------------------------------------------------------------------------
extern "C" void kernel_launch(void* const* d_in, const int* in_sizes, int n_in,
                              void* d_out, int out_size, void* d_ws, size_t ws_size,
                              hipStream_t stream) {
  const float* x    = (const float*)d_in[0];
  const float* Wqkv = (const float*)d_in[1];
  const float* Wout = (const float*)d_in[2];
  char* ws = (char*)d_ws;
  // workspace layout (MiB offsets)
  short* xb    = (short*)(ws);                        // 8 MiB  [4096][1024]
  short* WqkvT = (short*)(ws + ((size_t)8 << 20));    // 6 MiB  [3072][1024] (perm'd q/k cols)
  short* WoutT = (short*)(ws + ((size_t)14 << 20));   // 2 MiB  [1024][1024]
  short* qb    = (short*)(ws + ((size_t)40 << 20));   // 8 MiB  [32][2048][64]
  short* kb    = (short*)(ws + ((size_t)48 << 20));   // 8 MiB
  short* vT    = (short*)(ws + ((size_t)56 << 20));   // 8 MiB  [32][64][2048]
  short* attn  = (short*)(ws + ((size_t)64 << 20));   // 8 MiB  [4096][1024]
  float* cs    = (float*)(ws + ((size_t)72 << 20));   // 0.5 MiB [2048][32][2]

  cs_kernel<<<dim3(256), 256, 0, stream>>>(cs);
  conv_kernel<<<dim3(2048), 256, 0, stream>>>(x, xb);                              // x -> bf16
  transw_kernel<true><<<dim3(48, 16), 256, 0, stream>>>(Wqkv, WqkvT, 1024, 3072);  // Wqkv^T (perm)
  transw_kernel<false><<<dim3(16, 16), 256, 0, stream>>>(Wout, WoutT, 1024, 1024); // Wout^T
  // GEMM1 (256x128 tile) with fused RoPE + V-transpose epilogue
  gemm_bt_kernel<2><<<dim3(384), 512, 0, stream>>>(xb, WqkvT, nullptr, qb, kb, vT, cs,
                                                   4096, 3072, 1024, 24);
  attn_kernel<<<dim3(256), 512, 0, stream>>>(qb, kb, vT, attn);
  gemm_bt_kernel<0><<<dim3(128), 512, 0, stream>>>(attn, WoutT, (float*)d_out,
                                                   nullptr, nullptr, nullptr, nullptr,
                                                   4096, 1024, 1024, 8);
}

// Round 19
// 132.599 us; speedup vs baseline: 1.3969x; 1.0598x over previous
//
#include <hip/hip_runtime.h>
#include <hip/hip_bf16.h>
#include <stdint.h>
#include <math.h>

using bf16x8 = __attribute__((ext_vector_type(8))) short;
using bf16x4 = __attribute__((ext_vector_type(4))) short;
using f32x4  = __attribute__((ext_vector_type(4))) float;

#define DEV static __device__ __forceinline__

// SESSION LEDGER:
//  - r6/7: v_cvt_pk_bf16_f32 INLINE ASM => NaN. BANNED. packbf (compiler) green.
//  - r4/r12: exp2-domain q-prescale => absmax 5.86e-3 (deterministic). BANNED.
//  - attn: r8 Q-split REGRESS, r11 KV-split NULL, r13 chain-cuts NULL,
//    r15 KVBLK=128 REGRESS, r17 8-wave merge WIN (82.8->72.9). PARKED.
//  - r10: BK=64 swizzled-glds GEMM green. r18: 256x128/8-wave GEMMs WIN
//    (total 152.1->140.5; staging/output -25%, barriers/output halved).
//  - r14: RoPE+V-transpose fused into GEMM1 epilogue (green).
//  - r19 (this): merge cs/conv/transw x2 (mutually independent) into ONE
//    block-range prep kernel — removes 3 launch gaps; bodies unchanged.
//    256x256 GEMM rejected: grid 192 < 256 CUs.

DEV float bf2f(short s) {
  union { unsigned u; float f; } v; v.u = ((unsigned)(unsigned short)s) << 16; return v.f;
}
DEV short f2bf(float f) {
  union { float ff; unsigned u; } v; v.ff = f;
  unsigned r = v.u + 0x7fffu + ((v.u >> 16) & 1u);
  return (short)(r >> 16);
}
DEV unsigned packbf(float a, float b) {  // lo16 = RNE(a), hi16 = RNE(b)
  __hip_bfloat162 h = __float22bfloat162_rn(make_float2(a, b));
  union { __hip_bfloat162 h2; unsigned u; } v; v.h2 = h; return v.u;
}

DEV f32x4 mfma16x16x32(bf16x8 a, bf16x8 b, f32x4 c) {
  return __builtin_amdgcn_mfma_f32_16x16x32_bf16(a, b, c, 0, 0, 0);
}

DEV void glds16(const void* g, void* l) {
  __builtin_amdgcn_global_load_lds(
      (__attribute__((address_space(1))) void*)(uintptr_t)(g),
      (__attribute__((address_space(3))) void*)(l), 16, 0, 0);
}

#define B_   2
#define N_   2048
#define DIM_ 1024
#define H_   16
#define DH_  64
#define BH_  (B_ * H_)
#define BN_  (B_ * N_)

// ---------------------------------------------------------------------------
// transpose body: fp32 [R][C] tile (cb,rb) -> bf16 [C][R], optional q/k col
// permutation pi(d)=32*(d>>5? ... ) — pi(d): j=d>>1, s=d&1 -> 32*(j>>4)+16*s+(j&15)
// ---------------------------------------------------------------------------
DEV void transw_body(const float* __restrict__ src, short* __restrict__ dst,
                     int R, int C, int cb, int rb, bool perm,
                     unsigned short* lds) {
  const int t = threadIdx.x;
  #pragma unroll
  for (int pass = 0; pass < 4; ++pass) {
    int r  = pass * 16 + (t >> 4);
    int cc = (t & 15) * 4;
    float4 v = *(const float4*)(src + (size_t)(rb + r) * C + cb + cc);
    lds[(cc + 0) * 65 + r] = (unsigned short)f2bf(v.x);
    lds[(cc + 1) * 65 + r] = (unsigned short)f2bf(v.y);
    lds[(cc + 2) * 65 + r] = (unsigned short)f2bf(v.z);
    lds[(cc + 3) * 65 + r] = (unsigned short)f2bf(v.w);
  }
  __syncthreads();
  const int cl = t >> 2, chunk = t & 3;
  bf16x8 o0, o1;
  #pragma unroll
  for (int j = 0; j < 8; ++j) {
    o0[j] = (short)lds[cl * 65 + chunk * 16 + j];
    o1[j] = (short)lds[cl * 65 + chunk * 16 + 8 + j];
  }
  int ocl = cl;
  if (perm && cb < 2048) {
    int j = cl >> 1, s2 = cl & 1;
    ocl = ((j >> 4) << 5) + (s2 << 4) + (j & 15);
  }
  size_t off = (size_t)(cb + ocl) * R + rb + chunk * 16;
  *(bf16x8*)(dst + off)     = o0;
  *(bf16x8*)(dst + off + 8) = o1;
}

// ---------------------------------------------------------------------------
// 1) prep: cs table + x->bf16 + Wqkv^T(perm) + Wout^T in ONE launch.
//    Block ranges (all 256 thr): [0,256) cs | [256,2304) conv |
//    [2304,3072) transw Wqkv (48x16) | [3072,3328) transw Wout (16x16).
//    Sub-tasks are mutually independent; branch is block-uniform.
// ---------------------------------------------------------------------------
__global__ __launch_bounds__(256) void prep_kernel(const float* __restrict__ x,
                                                   const float* __restrict__ Wqkv,
                                                   const float* __restrict__ Wout,
                                                   short* __restrict__ xb,
                                                   short* __restrict__ WqkvT,
                                                   short* __restrict__ WoutT,
                                                   float* __restrict__ cs) {
  __shared__ unsigned short lds[64 * 65];
  const int bid = blockIdx.x;
  const int t = threadIdx.x;
  if (bid < 256) {
    // cs table: cs[(n*32+j)*2] = cos(n * 10000^(-2j/64)), +1 = sin
    int tid = bid * 256 + t;
    int n = tid >> 5, j = tid & 31;
    float inv = powf(10000.0f, -(float)(2 * j) / 64.0f);
    float ang = (float)n * inv;
    cs[2 * tid]     = cosf(ang);
    cs[2 * tid + 1] = sinf(ang);
  } else if (bid < 2304) {
    // x fp32 -> bf16
    int i = ((bid - 256) * 256 + t) * 8;
    float4 a = *(const float4*)(x + i);
    float4 b = *(const float4*)(x + i + 4);
    bf16x8 o;
    o[0] = f2bf(a.x); o[1] = f2bf(a.y); o[2] = f2bf(a.z); o[3] = f2bf(a.w);
    o[4] = f2bf(b.x); o[5] = f2bf(b.y); o[6] = f2bf(b.z); o[7] = f2bf(b.w);
    *(bf16x8*)(xb + i) = o;
  } else if (bid < 3072) {
    const int idx = bid - 2304;            // 0..767 = 48 x 16
    transw_body(Wqkv, WqkvT, 1024, 3072, (idx % 48) * 64, (idx / 48) * 64,
                true, lds);
  } else {
    const int idx = bid - 3072;            // 0..255 = 16 x 16
    transw_body(Wout, WoutT, 1024, 1024, (idx % 16) * 64, (idx / 16) * 64,
                false, lds);
  }
}

// ---------------------------------------------------------------------------
// 4) GEMM: C = A @ BT^T. 256x128 tile, BK=64, 8 waves (512 thr), chunk-XOR
//    swizzled glds source. Per-wave 64x64 quadrant: wm=w>>1 (0..3), wn=w&1.
//    MODE 0: f32 output. MODE 2: fused QKV epilogue (RoPE via perm'd W cols
//    -> qb/kb; V transposed -> vT). Bijective XCD swizzle (nwg%8==0).
// ---------------------------------------------------------------------------
template <int MODE>
__global__ __launch_bounds__(512) void gemm_bt_kernel(const short* __restrict__ A,
                                                      const short* __restrict__ BT,
                                                      float* __restrict__ Cout,
                                                      short* __restrict__ qb,
                                                      short* __restrict__ kb,
                                                      short* __restrict__ vT,
                                                      const float* __restrict__ cs,
                                                      int M, int N, int K, int gx) {
  __shared__ short As[256 * 64];   // 32 KB
  __shared__ short Bs[128 * 64];   // 16 KB
  const int nwg = gridDim.x;
  const int bid = blockIdx.x;
  const int swz = (bid & 7) * (nwg >> 3) + (bid >> 3);  // bijective: nwg%8==0
  const int bx = swz % gx, by = swz / gx;
  const int t = threadIdx.x;                // 0..511
  const int lane = t & 63, w = t >> 6;      // 8 waves
  const int c = lane & 15, g = lane >> 4;
  const int wm = w >> 1, wn = w & 1;
  const int mbase = by * 256, nbase = bx * 128;
  const short* Ab = A + (size_t)mbase * K;
  const short* Bb = BT + (size_t)nbase * K;
  f32x4 acc[4][4] = {};
  for (int kb2 = 0; kb2 < K; kb2 += 64) {
    #pragma unroll
    for (int i = 0; i < 4; ++i) {            // A: 2048 chunks
      const int idx = i * 512 + t;
      const int row = idx >> 3, p = idx & 7;
      const int gc = ((p ^ (row & 7)) << 3);
      glds16(Ab + (size_t)row * K + kb2 + gc, As + idx * 8);
    }
    #pragma unroll
    for (int i = 0; i < 2; ++i) {            // B: 1024 chunks
      const int idx = i * 512 + t;
      const int row = idx >> 3, p = idx & 7;
      const int gc = ((p ^ (row & 7)) << 3);
      glds16(Bb + (size_t)row * K + kb2 + gc, Bs + idx * 8);
    }
    __syncthreads();
    bf16x8 af[4][2], bfr[4][2];
    #pragma unroll
    for (int mi = 0; mi < 4; ++mi) {
      const int r = wm * 64 + mi * 16 + c;   // 0..255
      #pragma unroll
      for (int kk = 0; kk < 2; ++kk)
        af[mi][kk] = *(const bf16x8*)&As[r * 64 + (((kk * 4 + g) ^ (r & 7)) << 3)];
    }
    #pragma unroll
    for (int ni = 0; ni < 4; ++ni) {
      const int r = wn * 64 + ni * 16 + c;   // 0..127
      #pragma unroll
      for (int kk = 0; kk < 2; ++kk)
        bfr[ni][kk] = *(const bf16x8*)&Bs[r * 64 + (((kk * 4 + g) ^ (r & 7)) << 3)];
    }
    #pragma unroll
    for (int kk = 0; kk < 2; ++kk)
      #pragma unroll
      for (int mi = 0; mi < 4; ++mi)
        #pragma unroll
        for (int ni = 0; ni < 4; ++ni)
          acc[mi][ni] = mfma16x16x32(af[mi][kk], bfr[ni][kk], acc[mi][ni]);
    __syncthreads();
  }
  if constexpr (MODE == 0) {
    #pragma unroll
    for (int mi = 0; mi < 4; ++mi) {
      const int row = mbase + wm * 64 + mi * 16 + g * 4;
      #pragma unroll
      for (int ni = 0; ni < 4; ++ni) {
        const int col = nbase + wn * 64 + ni * 16 + c;
        #pragma unroll
        for (int r = 0; r < 4; ++r)
          Cout[(size_t)(row + r) * N + col] = acc[mi][ni][r];
      }
    }
  } else {
    const int col0 = nbase + wn * 64;     // head base; one head per warp
    const int i3 = col0 >> 10;            // 0=q, 1=k, 2=v
    const int h  = (col0 >> 6) & 15;
    if (i3 < 2) {
      // lane c holds logical d pairs: (2c,2c+1) at ni=0,1 ; (2c+32,2c+33) at ni=2,3
      short* dst0 = (i3 == 0) ? qb : kb;
      const float sc = (i3 == 0) ? 0.125f : 1.0f;
      #pragma unroll
      for (int mi = 0; mi < 4; ++mi) {
        const int row0 = mbase + wm * 64 + mi * 16 + g * 4;
        #pragma unroll
        for (int r = 0; r < 4; ++r) {
          const int row = row0 + r;
          const int n = row & 2047, b = row >> 11;
          short* dp = dst0 + ((size_t)(b * H_ + h) * N_ + n) * DH_;
          float2 cs0 = ((const float2*)cs)[n * 32 + c];
          float2 cs1 = ((const float2*)cs)[n * 32 + c + 16];
          float t1 = acc[mi][0][r], t2 = acc[mi][1][r];
          float t3 = acc[mi][2][r], t4 = acc[mi][3][r];
          unsigned u0 = packbf((t1 * cs0.x - t2 * cs0.y) * sc,
                               (t1 * cs0.y + t2 * cs0.x) * sc);
          unsigned u1 = packbf((t3 * cs1.x - t4 * cs1.y) * sc,
                               (t3 * cs1.y + t4 * cs1.x) * sc);
          *(unsigned*)(dp + 2 * c)      = u0;   // d = 2c, 2c+1
          *(unsigned*)(dp + 32 + 2 * c) = u1;   // d = 2c+32, 2c+33
        }
      }
    } else {
      // V: write transposed directly: vT[bh][d][n]
      #pragma unroll
      for (int mi = 0; mi < 4; ++mi) {
        const int row0 = mbase + wm * 64 + mi * 16 + g * 4;
        const int n0 = row0 & 2047, b = row0 >> 11;
        const int bh = b * H_ + h;
        #pragma unroll
        for (int ni = 0; ni < 4; ++ni) {
          const int dd = ni * 16 + c;
          bf16x4 ov;
          #pragma unroll
          for (int r = 0; r < 4; ++r) ov[r] = f2bf(acc[mi][ni][r]);
          *(bf16x4*)(vT + ((size_t)bh * DH_ + dd) * N_ + n0) = ov;
        }
      }
    }
  }
}

// ---------------------------------------------------------------------------
// 7) Flash attention — r17 WIN form, UNCHANGED. 8 waves / 256 q-rows per
//    block; K/V staged once for 8 consumer waves; 256 blocks = 1/CU.
// ---------------------------------------------------------------------------
__global__ __launch_bounds__(512) void attn_kernel(const short* __restrict__ qb,
                                                   const short* __restrict__ kb,
                                                   const short* __restrict__ vT,
                                                   short* __restrict__ attn_out) {
  __shared__ short Kt[2][4096];   // 8 KB per buf: [row 0..63][chunk 0..7][8]
  __shared__ short Vt[2][4096];
  const int t = threadIdx.x;                // 0..511
  const int lane = t & 63, w = t >> 6;      // 8 waves
  const int c = lane & 15, g = lane >> 4;
  const int bid = blockIdx.x;               // 256 blocks, 1D
  const int xcd = bid & 7, slot = bid >> 3; // slot 0..31
  const int bh = xcd + ((slot >> 3) << 3);  // 8 q-blocks of bh share an XCD
  const int xb = slot & 7;
  const int qbase = xb * 256 + w * 32;
  const short* kbase = kb + (size_t)bh * N_ * DH_;
  const short* vbase = vT + (size_t)bh * DH_ * N_;

  // staging map: 1 chunk per thread per array (512 chunks total each)
  const int s_row = t >> 3, s_p = t & 7;
  const int s_dst = s_row * 64 + ((s_p ^ (s_row & 7)) << 3);

  // Q fragments held in registers for the whole kv loop; q pre-scaled 1/8
  bf16x8 qlo[2], qhi[2];
  #pragma unroll
  for (int qf = 0; qf < 2; ++qf) {
    const short* qp = qb + ((size_t)bh * N_ + qbase + qf * 16 + c) * DH_;
    qlo[qf] = *(const bf16x8*)(qp + g * 8);
    qhi[qf] = *(const bf16x8*)(qp + 32 + g * 8);
  }

  float M[2] = {-INFINITY, -INFINITY};
  float L[2] = {0.f, 0.f};
  f32x4 o[4][2] = {};
  bf16x8 kr, vr;

  // prologue: load tile 0 -> regs, write buf 0, barrier
  kr = *(const bf16x8*)(kbase + (size_t)s_row * DH_ + s_p * 8);
  vr = *(const bf16x8*)(vbase + (size_t)s_row * N_ + s_p * 8);
  *(bf16x8*)(&Kt[0][s_dst]) = kr;
  *(bf16x8*)(&Vt[0][s_dst]) = vr;
  __syncthreads();

  for (int it = 0; it < 32; ++it) {
    const int cur = it & 1;
    const int pf_valid = (it + 1 < 32);
    if (pf_valid) {  // issue next-tile loads BEFORE compute (overlap)
      const int kv = (it + 1) * 64;
      kr = *(const bf16x8*)(kbase + (size_t)(kv + s_row) * DH_ + s_p * 8);
      vr = *(const bf16x8*)(vbase + (size_t)s_row * N_ + kv + s_p * 8);
    }
    // --- QK^T: s lane holds S[q=qf*16+c][j=it*64+jt*16+g*4+r] ---
    f32x4 s[4][2] = {};
    __builtin_amdgcn_s_setprio(1);
    #pragma unroll
    for (int jt = 0; jt < 4; ++jt) {
      const int r_ = jt * 16 + c;
      const short* kt = &Kt[cur][r_ * 64];
      bf16x8 k0 = *(const bf16x8*)(kt + ((g ^ (r_ & 7)) << 3));
      bf16x8 k1 = *(const bf16x8*)(kt + (((g + 4) ^ (r_ & 7)) << 3));
      #pragma unroll
      for (int qf = 0; qf < 2; ++qf) {
        s[jt][qf] = mfma16x16x32(k0, qlo[qf], s[jt][qf]);
        s[jt][qf] = mfma16x16x32(k1, qhi[qf], s[jt][qf]);
      }
    }
    __builtin_amdgcn_s_setprio(0);
    // --- online softmax: exact-skip rescale + tree sum ---
    bf16x8 pf[2][2];
    #pragma unroll
    for (int qf = 0; qf < 2; ++qf) {
      float m0 = fmaxf(fmaxf(s[0][qf][0], s[0][qf][1]), s[0][qf][2]);
      float m1 = fmaxf(fmaxf(s[0][qf][3], s[1][qf][0]), s[1][qf][1]);
      float m2 = fmaxf(fmaxf(s[1][qf][2], s[1][qf][3]), s[2][qf][0]);
      float m3 = fmaxf(fmaxf(s[2][qf][1], s[2][qf][2]), s[2][qf][3]);
      float m4 = fmaxf(fmaxf(s[3][qf][0], s[3][qf][1]), s[3][qf][2]);
      float mx = fmaxf(fmaxf(fmaxf(m0, m1), fmaxf(m2, m3)),
                       fmaxf(m4, s[3][qf][3]));
      mx = fmaxf(mx, __shfl_xor(mx, 16));
      mx = fmaxf(mx, __shfl_xor(mx, 32));
      if (__any(mx > M[qf])) {   // else corr==expf(0)==1 for all lanes: EXACT skip
        const float mnew = fmaxf(M[qf], mx);
        const float corr = __expf(M[qf] - mnew);  // exp(-inf)=0 first tile
        L[qf] *= corr;
        #pragma unroll
        for (int dt = 0; dt < 4; ++dt) o[dt][qf] *= corr;
        M[qf] = mnew;
      }
      #pragma unroll
      for (int jt = 0; jt < 4; ++jt)
        #pragma unroll
        for (int r = 0; r < 4; ++r)
          s[jt][qf][r] = __expf(s[jt][qf][r] - M[qf]);
      float t0 = (s[0][qf][0] + s[0][qf][1]) + (s[0][qf][2] + s[0][qf][3]);
      float t1 = (s[1][qf][0] + s[1][qf][1]) + (s[1][qf][2] + s[1][qf][3]);
      float t2 = (s[2][qf][0] + s[2][qf][1]) + (s[2][qf][2] + s[2][qf][3]);
      float t3 = (s[3][qf][0] + s[3][qf][1]) + (s[3][qf][2] + s[3][qf][3]);
      float rs = (t0 + t1) + (t2 + t3);
      rs += __shfl_xor(rs, 16);
      rs += __shfl_xor(rs, 32);
      L[qf] += rs;
      union { unsigned u[4]; bf16x8 v; } P0, P1;
      P0.u[0] = packbf(s[0][qf][0], s[0][qf][1]);
      P0.u[1] = packbf(s[0][qf][2], s[0][qf][3]);
      P0.u[2] = packbf(s[1][qf][0], s[1][qf][1]);
      P0.u[3] = packbf(s[1][qf][2], s[1][qf][3]);
      P1.u[0] = packbf(s[2][qf][0], s[2][qf][1]);
      P1.u[1] = packbf(s[2][qf][2], s[2][qf][3]);
      P1.u[2] = packbf(s[3][qf][0], s[3][qf][1]);
      P1.u[3] = packbf(s[3][qf][2], s[3][qf][3]);
      pf[qf][0] = P0.v;
      pf[qf][1] = P1.v;
    }
    // --- PV: A = V^T rows d, slot map j = kf*32 + (s<4 ? g*4+s : 16+g*4+s-4)
    __builtin_amdgcn_s_setprio(1);
    #pragma unroll
    for (int dt = 0; dt < 4; ++dt) {
      const int d = dt * 16 + c;
      const short* vt = &Vt[cur][d * 64];
      const int dx = d & 7;
      #pragma unroll
      for (int kf = 0; kf < 2; ++kf) {
        const int e0 = kf * 32 + g * 4;
        const int e1 = e0 + 16;
        bf16x4 a0 = *(const bf16x4*)(vt + ((((e0 >> 3) ^ dx) << 3) | (e0 & 7)));
        bf16x4 a1 = *(const bf16x4*)(vt + ((((e1 >> 3) ^ dx) << 3) | (e1 & 7)));
        bf16x8 vf = __builtin_shufflevector(a0, a1, 0, 1, 2, 3, 4, 5, 6, 7);
        o[dt][0] = mfma16x16x32(vf, pf[0][kf], o[dt][0]);
        o[dt][1] = mfma16x16x32(vf, pf[1][kf], o[dt][1]);
      }
    }
    __builtin_amdgcn_s_setprio(0);
    // --- write-late: store prefetched regs into the idle buffer ---
    if (pf_valid) {
      *(bf16x8*)(&Kt[cur ^ 1][s_dst]) = kr;
      *(bf16x8*)(&Vt[cur ^ 1][s_dst]) = vr;
    }
    __syncthreads();
  }

  const int b = bh >> 4, h = bh & 15;
  #pragma unroll
  for (int qf = 0; qf < 2; ++qf) {
    const float inv = 1.0f / L[qf];
    short* op = attn_out + ((size_t)b * N_ + qbase + qf * 16 + c) * (H_ * DH_) + h * DH_;
    #pragma unroll
    for (int dt = 0; dt < 4; ++dt) {
      bf16x4 ov;
      #pragma unroll
      for (int r = 0; r < 4; ++r) ov[r] = f2bf(o[dt][qf][r] * inv);
      *(bf16x4*)(op + dt * 16 + g * 4) = ov;
    }
  }
}

// ---------------------------------------------------------------------------
extern "C" void kernel_launch(void* const* d_in, const int* in_sizes, int n_in,
                              void* d_out, int out_size, void* d_ws, size_t ws_size,
                              hipStream_t stream) {
  const float* x    = (const float*)d_in[0];
  const float* Wqkv = (const float*)d_in[1];
  const float* Wout = (const float*)d_in[2];
  char* ws = (char*)d_ws;
  // workspace layout (MiB offsets)
  short* xb    = (short*)(ws);                        // 8 MiB  [4096][1024]
  short* WqkvT = (short*)(ws + ((size_t)8 << 20));    // 6 MiB  [3072][1024] (perm'd q/k cols)
  short* WoutT = (short*)(ws + ((size_t)14 << 20));   // 2 MiB  [1024][1024]
  short* qb    = (short*)(ws + ((size_t)40 << 20));   // 8 MiB  [32][2048][64]
  short* kb    = (short*)(ws + ((size_t)48 << 20));   // 8 MiB
  short* vT    = (short*)(ws + ((size_t)56 << 20));   // 8 MiB  [32][64][2048]
  short* attn  = (short*)(ws + ((size_t)64 << 20));   // 8 MiB  [4096][1024]
  float* cs    = (float*)(ws + ((size_t)72 << 20));   // 0.5 MiB [2048][32][2]

  // 1 launch: cs + conv + Wqkv^T(perm) + Wout^T (mutually independent)
  prep_kernel<<<dim3(3328), 256, 0, stream>>>(x, Wqkv, Wout, xb, WqkvT, WoutT, cs);
  // GEMM1 (256x128 tile) with fused RoPE + V-transpose epilogue
  gemm_bt_kernel<2><<<dim3(384), 512, 0, stream>>>(xb, WqkvT, nullptr, qb, kb, vT, cs,
                                                   4096, 3072, 1024, 24);
  attn_kernel<<<dim3(256), 512, 0, stream>>>(qb, kb, vT, attn);
  gemm_bt_kernel<0><<<dim3(128), 512, 0, stream>>>(attn, WoutT, (float*)d_out,
                                                   nullptr, nullptr, nullptr, nullptr,
                                                   4096, 1024, 1024, 8);
}

// Round 20
// 126.556 us; speedup vs baseline: 1.4636x; 1.0477x over previous
//
#include <hip/hip_runtime.h>
#include <hip/hip_bf16.h>
#include <stdint.h>
#include <math.h>

using bf16x8 = __attribute__((ext_vector_type(8))) short;
using bf16x4 = __attribute__((ext_vector_type(4))) short;
using f32x4  = __attribute__((ext_vector_type(4))) float;

#define DEV static __device__ __forceinline__

// SESSION LEDGER:
//  - r6/7: v_cvt_pk_bf16_f32 INLINE ASM => NaN. BANNED. packbf (compiler) green.
//  - r4/r12: exp2-domain q-prescale => absmax 5.86e-3 (deterministic). BANNED.
//  - attn: r8 Q-split REGRESS, r11 KV-split NULL, r13 chain-cuts NULL,
//    r15 KVBLK=128 REGRESS, r17 8-wave merge WIN (82.8->72.9). PARKED.
//  - r10: BK=64 swizzled-glds GEMM green. r18: 256x128/8-wave GEMMs WIN.
//  - r14: RoPE+V-transpose fused into GEMM1 epilogue (green).
//  - r19: single prep launch WIN (140.5->132.6).
//  - r20 (this): GEMM2 only -> 128x128 tile / 8 waves (2x4 wave grid):
//    256 blocks = 2/CU = 16 waves/CU on ALL CUs (was 128 blocks = half GPU).
//    Per-output accumulation sequence identical => bit-identical C.
//    GEMM1 (r18 winner) untouched. If regress: r19 form is session-final.

DEV float bf2f(short s) {
  union { unsigned u; float f; } v; v.u = ((unsigned)(unsigned short)s) << 16; return v.f;
}
DEV short f2bf(float f) {
  union { float ff; unsigned u; } v; v.ff = f;
  unsigned r = v.u + 0x7fffu + ((v.u >> 16) & 1u);
  return (short)(r >> 16);
}
DEV unsigned packbf(float a, float b) {  // lo16 = RNE(a), hi16 = RNE(b)
  __hip_bfloat162 h = __float22bfloat162_rn(make_float2(a, b));
  union { __hip_bfloat162 h2; unsigned u; } v; v.h2 = h; return v.u;
}

DEV f32x4 mfma16x16x32(bf16x8 a, bf16x8 b, f32x4 c) {
  return __builtin_amdgcn_mfma_f32_16x16x32_bf16(a, b, c, 0, 0, 0);
}

DEV void glds16(const void* g, void* l) {
  __builtin_amdgcn_global_load_lds(
      (__attribute__((address_space(1))) void*)(uintptr_t)(g),
      (__attribute__((address_space(3))) void*)(l), 16, 0, 0);
}

#define B_   2
#define N_   2048
#define DIM_ 1024
#define H_   16
#define DH_  64
#define BH_  (B_ * H_)
#define BN_  (B_ * N_)

// ---------------------------------------------------------------------------
// transpose body: fp32 [R][C] tile (cb,rb) -> bf16 [C][R], optional q/k col
// permutation pi(d): j=d>>1, s=d&1 -> 32*(j>>4)+16*s+(j&15)
// ---------------------------------------------------------------------------
DEV void transw_body(const float* __restrict__ src, short* __restrict__ dst,
                     int R, int C, int cb, int rb, bool perm,
                     unsigned short* lds) {
  const int t = threadIdx.x;
  #pragma unroll
  for (int pass = 0; pass < 4; ++pass) {
    int r  = pass * 16 + (t >> 4);
    int cc = (t & 15) * 4;
    float4 v = *(const float4*)(src + (size_t)(rb + r) * C + cb + cc);
    lds[(cc + 0) * 65 + r] = (unsigned short)f2bf(v.x);
    lds[(cc + 1) * 65 + r] = (unsigned short)f2bf(v.y);
    lds[(cc + 2) * 65 + r] = (unsigned short)f2bf(v.z);
    lds[(cc + 3) * 65 + r] = (unsigned short)f2bf(v.w);
  }
  __syncthreads();
  const int cl = t >> 2, chunk = t & 3;
  bf16x8 o0, o1;
  #pragma unroll
  for (int j = 0; j < 8; ++j) {
    o0[j] = (short)lds[cl * 65 + chunk * 16 + j];
    o1[j] = (short)lds[cl * 65 + chunk * 16 + 8 + j];
  }
  int ocl = cl;
  if (perm && cb < 2048) {
    int j = cl >> 1, s2 = cl & 1;
    ocl = ((j >> 4) << 5) + (s2 << 4) + (j & 15);
  }
  size_t off = (size_t)(cb + ocl) * R + rb + chunk * 16;
  *(bf16x8*)(dst + off)     = o0;
  *(bf16x8*)(dst + off + 8) = o1;
}

// ---------------------------------------------------------------------------
// 1) prep: cs table + x->bf16 + Wqkv^T(perm) + Wout^T in ONE launch.
//    Block ranges (all 256 thr): [0,256) cs | [256,2304) conv |
//    [2304,3072) transw Wqkv (48x16) | [3072,3328) transw Wout (16x16).
// ---------------------------------------------------------------------------
__global__ __launch_bounds__(256) void prep_kernel(const float* __restrict__ x,
                                                   const float* __restrict__ Wqkv,
                                                   const float* __restrict__ Wout,
                                                   short* __restrict__ xb,
                                                   short* __restrict__ WqkvT,
                                                   short* __restrict__ WoutT,
                                                   float* __restrict__ cs) {
  __shared__ unsigned short lds[64 * 65];
  const int bid = blockIdx.x;
  const int t = threadIdx.x;
  if (bid < 256) {
    int tid = bid * 256 + t;
    int n = tid >> 5, j = tid & 31;
    float inv = powf(10000.0f, -(float)(2 * j) / 64.0f);
    float ang = (float)n * inv;
    cs[2 * tid]     = cosf(ang);
    cs[2 * tid + 1] = sinf(ang);
  } else if (bid < 2304) {
    int i = ((bid - 256) * 256 + t) * 8;
    float4 a = *(const float4*)(x + i);
    float4 b = *(const float4*)(x + i + 4);
    bf16x8 o;
    o[0] = f2bf(a.x); o[1] = f2bf(a.y); o[2] = f2bf(a.z); o[3] = f2bf(a.w);
    o[4] = f2bf(b.x); o[5] = f2bf(b.y); o[6] = f2bf(b.z); o[7] = f2bf(b.w);
    *(bf16x8*)(xb + i) = o;
  } else if (bid < 3072) {
    const int idx = bid - 2304;            // 0..767 = 48 x 16
    transw_body(Wqkv, WqkvT, 1024, 3072, (idx % 48) * 64, (idx / 48) * 64,
                true, lds);
  } else {
    const int idx = bid - 3072;            // 0..255 = 16 x 16
    transw_body(Wout, WoutT, 1024, 1024, (idx % 16) * 64, (idx / 16) * 64,
                false, lds);
  }
}

// ---------------------------------------------------------------------------
// 4) GEMM1: C = A @ BT^T. 256x128 tile, BK=64, 8 waves (512 thr), chunk-XOR
//    swizzled glds source. Per-wave 64x64 quadrant: wm=w>>1 (0..3), wn=w&1.
//    Fused QKV epilogue (RoPE via perm'd W cols -> qb/kb; V transposed -> vT).
//    Bijective XCD swizzle (nwg%8==0). (r18 WIN form, untouched.)
// ---------------------------------------------------------------------------
__global__ __launch_bounds__(512) void gemm_qkv_kernel(const short* __restrict__ A,
                                                       const short* __restrict__ BT,
                                                       short* __restrict__ qb,
                                                       short* __restrict__ kb,
                                                       short* __restrict__ vT,
                                                       const float* __restrict__ cs,
                                                       int M, int N, int K, int gx) {
  __shared__ short As[256 * 64];   // 32 KB
  __shared__ short Bs[128 * 64];   // 16 KB
  const int nwg = gridDim.x;
  const int bid = blockIdx.x;
  const int swz = (bid & 7) * (nwg >> 3) + (bid >> 3);  // bijective: nwg%8==0
  const int bx = swz % gx, by = swz / gx;
  const int t = threadIdx.x;                // 0..511
  const int lane = t & 63, w = t >> 6;      // 8 waves
  const int c = lane & 15, g = lane >> 4;
  const int wm = w >> 1, wn = w & 1;
  const int mbase = by * 256, nbase = bx * 128;
  const short* Ab = A + (size_t)mbase * K;
  const short* Bb = BT + (size_t)nbase * K;
  f32x4 acc[4][4] = {};
  for (int kb2 = 0; kb2 < K; kb2 += 64) {
    #pragma unroll
    for (int i = 0; i < 4; ++i) {            // A: 2048 chunks
      const int idx = i * 512 + t;
      const int row = idx >> 3, p = idx & 7;
      const int gc = ((p ^ (row & 7)) << 3);
      glds16(Ab + (size_t)row * K + kb2 + gc, As + idx * 8);
    }
    #pragma unroll
    for (int i = 0; i < 2; ++i) {            // B: 1024 chunks
      const int idx = i * 512 + t;
      const int row = idx >> 3, p = idx & 7;
      const int gc = ((p ^ (row & 7)) << 3);
      glds16(Bb + (size_t)row * K + kb2 + gc, Bs + idx * 8);
    }
    __syncthreads();
    bf16x8 af[4][2], bfr[4][2];
    #pragma unroll
    for (int mi = 0; mi < 4; ++mi) {
      const int r = wm * 64 + mi * 16 + c;   // 0..255
      #pragma unroll
      for (int kk = 0; kk < 2; ++kk)
        af[mi][kk] = *(const bf16x8*)&As[r * 64 + (((kk * 4 + g) ^ (r & 7)) << 3)];
    }
    #pragma unroll
    for (int ni = 0; ni < 4; ++ni) {
      const int r = wn * 64 + ni * 16 + c;   // 0..127
      #pragma unroll
      for (int kk = 0; kk < 2; ++kk)
        bfr[ni][kk] = *(const bf16x8*)&Bs[r * 64 + (((kk * 4 + g) ^ (r & 7)) << 3)];
    }
    #pragma unroll
    for (int kk = 0; kk < 2; ++kk)
      #pragma unroll
      for (int mi = 0; mi < 4; ++mi)
        #pragma unroll
        for (int ni = 0; ni < 4; ++ni)
          acc[mi][ni] = mfma16x16x32(af[mi][kk], bfr[ni][kk], acc[mi][ni]);
    __syncthreads();
  }
  const int col0 = nbase + wn * 64;     // head base; one head per warp
  const int i3 = col0 >> 10;            // 0=q, 1=k, 2=v
  const int h  = (col0 >> 6) & 15;
  if (i3 < 2) {
    // lane c holds logical d pairs: (2c,2c+1) at ni=0,1 ; (2c+32,2c+33) at ni=2,3
    short* dst0 = (i3 == 0) ? qb : kb;
    const float sc = (i3 == 0) ? 0.125f : 1.0f;
    #pragma unroll
    for (int mi = 0; mi < 4; ++mi) {
      const int row0 = mbase + wm * 64 + mi * 16 + g * 4;
      #pragma unroll
      for (int r = 0; r < 4; ++r) {
        const int row = row0 + r;
        const int n = row & 2047, b = row >> 11;
        short* dp = dst0 + ((size_t)(b * H_ + h) * N_ + n) * DH_;
        float2 cs0 = ((const float2*)cs)[n * 32 + c];
        float2 cs1 = ((const float2*)cs)[n * 32 + c + 16];
        float t1 = acc[mi][0][r], t2 = acc[mi][1][r];
        float t3 = acc[mi][2][r], t4 = acc[mi][3][r];
        unsigned u0 = packbf((t1 * cs0.x - t2 * cs0.y) * sc,
                             (t1 * cs0.y + t2 * cs0.x) * sc);
        unsigned u1 = packbf((t3 * cs1.x - t4 * cs1.y) * sc,
                             (t3 * cs1.y + t4 * cs1.x) * sc);
        *(unsigned*)(dp + 2 * c)      = u0;   // d = 2c, 2c+1
        *(unsigned*)(dp + 32 + 2 * c) = u1;   // d = 2c+32, 2c+33
      }
    }
  } else {
    // V: write transposed directly: vT[bh][d][n]
    #pragma unroll
    for (int mi = 0; mi < 4; ++mi) {
      const int row0 = mbase + wm * 64 + mi * 16 + g * 4;
      const int n0 = row0 & 2047, b = row0 >> 11;
      const int bh = b * H_ + h;
      #pragma unroll
      for (int ni = 0; ni < 4; ++ni) {
        const int dd = ni * 16 + c;
        bf16x4 ov;
        #pragma unroll
        for (int r = 0; r < 4; ++r) ov[r] = f2bf(acc[mi][ni][r]);
        *(bf16x4*)(vT + ((size_t)bh * DH_ + dd) * N_ + n0) = ov;
      }
    }
  }
}

// ---------------------------------------------------------------------------
// 5) GEMM2: C[M][N] (f32) = A @ BT^T. 128x128 tile, BK=64, 8 waves in a
//    2x4 grid: wm=w>>2 owns 64 rows, wn=w&3 owns 32 cols; acc[4][2].
//    256 blocks = 2/CU = 16 waves/CU on all CUs (vs 128 blocks half-GPU).
//    Per-output accumulation sequence identical => bit-identical C.
// ---------------------------------------------------------------------------
__global__ __launch_bounds__(512) void gemm_out_kernel(const short* __restrict__ A,
                                                       const short* __restrict__ BT,
                                                       float* __restrict__ Cout,
                                                       int M, int N, int K, int gx) {
  __shared__ short As[128 * 64];   // 16 KB
  __shared__ short Bs[128 * 64];   // 16 KB
  const int nwg = gridDim.x;
  const int bid = blockIdx.x;
  const int swz = (bid & 7) * (nwg >> 3) + (bid >> 3);  // bijective: nwg%8==0
  const int bx = swz % gx, by = swz / gx;
  const int t = threadIdx.x;                // 0..511
  const int lane = t & 63, w = t >> 6;      // 8 waves
  const int c = lane & 15, g = lane >> 4;
  const int wm = w >> 2, wn = w & 3;        // 2x4 wave grid
  const int mbase = by * 128, nbase = bx * 128;
  const short* Ab = A + (size_t)mbase * K;
  const short* Bb = BT + (size_t)nbase * K;
  f32x4 acc[4][2] = {};
  for (int kb2 = 0; kb2 < K; kb2 += 64) {
    #pragma unroll
    for (int i = 0; i < 2; ++i) {            // A: 1024 chunks
      const int idx = i * 512 + t;
      const int row = idx >> 3, p = idx & 7;
      const int gc = ((p ^ (row & 7)) << 3);
      glds16(Ab + (size_t)row * K + kb2 + gc, As + idx * 8);
    }
    #pragma unroll
    for (int i = 0; i < 2; ++i) {            // B: 1024 chunks
      const int idx = i * 512 + t;
      const int row = idx >> 3, p = idx & 7;
      const int gc = ((p ^ (row & 7)) << 3);
      glds16(Bb + (size_t)row * K + kb2 + gc, Bs + idx * 8);
    }
    __syncthreads();
    bf16x8 af[4][2], bfr[2][2];
    #pragma unroll
    for (int mi = 0; mi < 4; ++mi) {
      const int r = wm * 64 + mi * 16 + c;   // 0..127
      #pragma unroll
      for (int kk = 0; kk < 2; ++kk)
        af[mi][kk] = *(const bf16x8*)&As[r * 64 + (((kk * 4 + g) ^ (r & 7)) << 3)];
    }
    #pragma unroll
    for (int ni = 0; ni < 2; ++ni) {
      const int r = wn * 32 + ni * 16 + c;   // 0..127
      #pragma unroll
      for (int kk = 0; kk < 2; ++kk)
        bfr[ni][kk] = *(const bf16x8*)&Bs[r * 64 + (((kk * 4 + g) ^ (r & 7)) << 3)];
    }
    #pragma unroll
    for (int kk = 0; kk < 2; ++kk)
      #pragma unroll
      for (int mi = 0; mi < 4; ++mi)
        #pragma unroll
        for (int ni = 0; ni < 2; ++ni)
          acc[mi][ni] = mfma16x16x32(af[mi][kk], bfr[ni][kk], acc[mi][ni]);
    __syncthreads();
  }
  #pragma unroll
  for (int mi = 0; mi < 4; ++mi) {
    const int row = mbase + wm * 64 + mi * 16 + g * 4;
    #pragma unroll
    for (int ni = 0; ni < 2; ++ni) {
      const int col = nbase + wn * 32 + ni * 16 + c;
      #pragma unroll
      for (int r = 0; r < 4; ++r)
        Cout[(size_t)(row + r) * N + col] = acc[mi][ni][r];
    }
  }
}

// ---------------------------------------------------------------------------
// 7) Flash attention — r17 WIN form, UNCHANGED. 8 waves / 256 q-rows per
//    block; K/V staged once for 8 consumer waves; 256 blocks = 1/CU.
// ---------------------------------------------------------------------------
__global__ __launch_bounds__(512) void attn_kernel(const short* __restrict__ qb,
                                                   const short* __restrict__ kb,
                                                   const short* __restrict__ vT,
                                                   short* __restrict__ attn_out) {
  __shared__ short Kt[2][4096];   // 8 KB per buf: [row 0..63][chunk 0..7][8]
  __shared__ short Vt[2][4096];
  const int t = threadIdx.x;                // 0..511
  const int lane = t & 63, w = t >> 6;      // 8 waves
  const int c = lane & 15, g = lane >> 4;
  const int bid = blockIdx.x;               // 256 blocks, 1D
  const int xcd = bid & 7, slot = bid >> 3; // slot 0..31
  const int bh = xcd + ((slot >> 3) << 3);  // 8 q-blocks of bh share an XCD
  const int xb = slot & 7;
  const int qbase = xb * 256 + w * 32;
  const short* kbase = kb + (size_t)bh * N_ * DH_;
  const short* vbase = vT + (size_t)bh * DH_ * N_;

  // staging map: 1 chunk per thread per array (512 chunks total each)
  const int s_row = t >> 3, s_p = t & 7;
  const int s_dst = s_row * 64 + ((s_p ^ (s_row & 7)) << 3);

  // Q fragments held in registers for the whole kv loop; q pre-scaled 1/8
  bf16x8 qlo[2], qhi[2];
  #pragma unroll
  for (int qf = 0; qf < 2; ++qf) {
    const short* qp = qb + ((size_t)bh * N_ + qbase + qf * 16 + c) * DH_;
    qlo[qf] = *(const bf16x8*)(qp + g * 8);
    qhi[qf] = *(const bf16x8*)(qp + 32 + g * 8);
  }

  float M[2] = {-INFINITY, -INFINITY};
  float L[2] = {0.f, 0.f};
  f32x4 o[4][2] = {};
  bf16x8 kr, vr;

  // prologue: load tile 0 -> regs, write buf 0, barrier
  kr = *(const bf16x8*)(kbase + (size_t)s_row * DH_ + s_p * 8);
  vr = *(const bf16x8*)(vbase + (size_t)s_row * N_ + s_p * 8);
  *(bf16x8*)(&Kt[0][s_dst]) = kr;
  *(bf16x8*)(&Vt[0][s_dst]) = vr;
  __syncthreads();

  for (int it = 0; it < 32; ++it) {
    const int cur = it & 1;
    const int pf_valid = (it + 1 < 32);
    if (pf_valid) {  // issue next-tile loads BEFORE compute (overlap)
      const int kv = (it + 1) * 64;
      kr = *(const bf16x8*)(kbase + (size_t)(kv + s_row) * DH_ + s_p * 8);
      vr = *(const bf16x8*)(vbase + (size_t)s_row * N_ + kv + s_p * 8);
    }
    // --- QK^T: s lane holds S[q=qf*16+c][j=it*64+jt*16+g*4+r] ---
    f32x4 s[4][2] = {};
    __builtin_amdgcn_s_setprio(1);
    #pragma unroll
    for (int jt = 0; jt < 4; ++jt) {
      const int r_ = jt * 16 + c;
      const short* kt = &Kt[cur][r_ * 64];
      bf16x8 k0 = *(const bf16x8*)(kt + ((g ^ (r_ & 7)) << 3));
      bf16x8 k1 = *(const bf16x8*)(kt + (((g + 4) ^ (r_ & 7)) << 3));
      #pragma unroll
      for (int qf = 0; qf < 2; ++qf) {
        s[jt][qf] = mfma16x16x32(k0, qlo[qf], s[jt][qf]);
        s[jt][qf] = mfma16x16x32(k1, qhi[qf], s[jt][qf]);
      }
    }
    __builtin_amdgcn_s_setprio(0);
    // --- online softmax: exact-skip rescale + tree sum ---
    bf16x8 pf[2][2];
    #pragma unroll
    for (int qf = 0; qf < 2; ++qf) {
      float m0 = fmaxf(fmaxf(s[0][qf][0], s[0][qf][1]), s[0][qf][2]);
      float m1 = fmaxf(fmaxf(s[0][qf][3], s[1][qf][0]), s[1][qf][1]);
      float m2 = fmaxf(fmaxf(s[1][qf][2], s[1][qf][3]), s[2][qf][0]);
      float m3 = fmaxf(fmaxf(s[2][qf][1], s[2][qf][2]), s[2][qf][3]);
      float m4 = fmaxf(fmaxf(s[3][qf][0], s[3][qf][1]), s[3][qf][2]);
      float mx = fmaxf(fmaxf(fmaxf(m0, m1), fmaxf(m2, m3)),
                       fmaxf(m4, s[3][qf][3]));
      mx = fmaxf(mx, __shfl_xor(mx, 16));
      mx = fmaxf(mx, __shfl_xor(mx, 32));
      if (__any(mx > M[qf])) {   // else corr==expf(0)==1 for all lanes: EXACT skip
        const float mnew = fmaxf(M[qf], mx);
        const float corr = __expf(M[qf] - mnew);  // exp(-inf)=0 first tile
        L[qf] *= corr;
        #pragma unroll
        for (int dt = 0; dt < 4; ++dt) o[dt][qf] *= corr;
        M[qf] = mnew;
      }
      #pragma unroll
      for (int jt = 0; jt < 4; ++jt)
        #pragma unroll
        for (int r = 0; r < 4; ++r)
          s[jt][qf][r] = __expf(s[jt][qf][r] - M[qf]);
      float t0 = (s[0][qf][0] + s[0][qf][1]) + (s[0][qf][2] + s[0][qf][3]);
      float t1 = (s[1][qf][0] + s[1][qf][1]) + (s[1][qf][2] + s[1][qf][3]);
      float t2 = (s[2][qf][0] + s[2][qf][1]) + (s[2][qf][2] + s[2][qf][3]);
      float t3 = (s[3][qf][0] + s[3][qf][1]) + (s[3][qf][2] + s[3][qf][3]);
      float rs = (t0 + t1) + (t2 + t3);
      rs += __shfl_xor(rs, 16);
      rs += __shfl_xor(rs, 32);
      L[qf] += rs;
      union { unsigned u[4]; bf16x8 v; } P0, P1;
      P0.u[0] = packbf(s[0][qf][0], s[0][qf][1]);
      P0.u[1] = packbf(s[0][qf][2], s[0][qf][3]);
      P0.u[2] = packbf(s[1][qf][0], s[1][qf][1]);
      P0.u[3] = packbf(s[1][qf][2], s[1][qf][3]);
      P1.u[0] = packbf(s[2][qf][0], s[2][qf][1]);
      P1.u[1] = packbf(s[2][qf][2], s[2][qf][3]);
      P1.u[2] = packbf(s[3][qf][0], s[3][qf][1]);
      P1.u[3] = packbf(s[3][qf][2], s[3][qf][3]);
      pf[qf][0] = P0.v;
      pf[qf][1] = P1.v;
    }
    // --- PV: A = V^T rows d, slot map j = kf*32 + (s<4 ? g*4+s : 16+g*4+s-4)
    __builtin_amdgcn_s_setprio(1);
    #pragma unroll
    for (int dt = 0; dt < 4; ++dt) {
      const int d = dt * 16 + c;
      const short* vt = &Vt[cur][d * 64];
      const int dx = d & 7;
      #pragma unroll
      for (int kf = 0; kf < 2; ++kf) {
        const int e0 = kf * 32 + g * 4;
        const int e1 = e0 + 16;
        bf16x4 a0 = *(const bf16x4*)(vt + ((((e0 >> 3) ^ dx) << 3) | (e0 & 7)));
        bf16x4 a1 = *(const bf16x4*)(vt + ((((e1 >> 3) ^ dx) << 3) | (e1 & 7)));
        bf16x8 vf = __builtin_shufflevector(a0, a1, 0, 1, 2, 3, 4, 5, 6, 7);
        o[dt][0] = mfma16x16x32(vf, pf[0][kf], o[dt][0]);
        o[dt][1] = mfma16x16x32(vf, pf[1][kf], o[dt][1]);
      }
    }
    __builtin_amdgcn_s_setprio(0);
    // --- write-late: store prefetched regs into the idle buffer ---
    if (pf_valid) {
      *(bf16x8*)(&Kt[cur ^ 1][s_dst]) = kr;
      *(bf16x8*)(&Vt[cur ^ 1][s_dst]) = vr;
    }
    __syncthreads();
  }

  const int b = bh >> 4, h = bh & 15;
  #pragma unroll
  for (int qf = 0; qf < 2; ++qf) {
    const float inv = 1.0f / L[qf];
    short* op = attn_out + ((size_t)b * N_ + qbase + qf * 16 + c) * (H_ * DH_) + h * DH_;
    #pragma unroll
    for (int dt = 0; dt < 4; ++dt) {
      bf16x4 ov;
      #pragma unroll
      for (int r = 0; r < 4; ++r) ov[r] = f2bf(o[dt][qf][r] * inv);
      *(bf16x4*)(op + dt * 16 + g * 4) = ov;
    }
  }
}

// ---------------------------------------------------------------------------
extern "C" void kernel_launch(void* const* d_in, const int* in_sizes, int n_in,
                              void* d_out, int out_size, void* d_ws, size_t ws_size,
                              hipStream_t stream) {
  const float* x    = (const float*)d_in[0];
  const float* Wqkv = (const float*)d_in[1];
  const float* Wout = (const float*)d_in[2];
  char* ws = (char*)d_ws;
  // workspace layout (MiB offsets)
  short* xb    = (short*)(ws);                        // 8 MiB  [4096][1024]
  short* WqkvT = (short*)(ws + ((size_t)8 << 20));    // 6 MiB  [3072][1024] (perm'd q/k cols)
  short* WoutT = (short*)(ws + ((size_t)14 << 20));   // 2 MiB  [1024][1024]
  short* qb    = (short*)(ws + ((size_t)40 << 20));   // 8 MiB  [32][2048][64]
  short* kb    = (short*)(ws + ((size_t)48 << 20));   // 8 MiB
  short* vT    = (short*)(ws + ((size_t)56 << 20));   // 8 MiB  [32][64][2048]
  short* attn  = (short*)(ws + ((size_t)64 << 20));   // 8 MiB  [4096][1024]
  float* cs    = (float*)(ws + ((size_t)72 << 20));   // 0.5 MiB [2048][32][2]

  // 1 launch: cs + conv + Wqkv^T(perm) + Wout^T (mutually independent)
  prep_kernel<<<dim3(3328), 256, 0, stream>>>(x, Wqkv, Wout, xb, WqkvT, WoutT, cs);
  // GEMM1 (256x128 tile) with fused RoPE + V-transpose epilogue
  gemm_qkv_kernel<<<dim3(384), 512, 0, stream>>>(xb, WqkvT, qb, kb, vT, cs,
                                                 4096, 3072, 1024, 24);
  attn_kernel<<<dim3(256), 512, 0, stream>>>(qb, kb, vT, attn);
  // GEMM2 (128x128 tile, 8 waves, 256 blocks = full GPU)
  gemm_out_kernel<<<dim3(256), 512, 0, stream>>>(attn, WoutT, (float*)d_out,
                                                 4096, 1024, 1024, 8);
}